// Round 1
// baseline (1203.866 us; speedup 1.0000x reference)
//
#include <hip/hip_runtime.h>
#include <stdint.h>

// GINE net, MI355X. Pipeline:
//   k_detect  : edge_index int32-vs-int64 width detection (device-side, every call)
//   k_setup   : piecewise-linear edge-MLP coefficients A[65][64], B[65][64], thresholds t[64]
//   k_hist/scan1/scan2/scan3/k_scatter : CSR build (edges grouped by dst), payload src|p<<20, a
//   k_conv    : per-node aggregation u = (1+eps)*x + sum relu(x[src] + a*A_p + B_p)  (no atomics)
//   k_mlp     : node MLP relu((relu(u W1 + b1)) W2 + b2), thread-per-node, LDS row staging
//   k_classify: logits + log_softmax

__global__ void k_detect(const unsigned int* __restrict__ w, int* __restrict__ flag, int E) {
  int i = blockIdx.x * blockDim.x + threadIdx.x;
  int pred = (i < E) && (w[2 * (size_t)i + 1] != 0u);
  if (__any(pred) && (threadIdx.x & 63) == 0) atomicOr(flag, 1);
}

__global__ void k_setup(const float* __restrict__ w1, const float* __restrict__ b1,
                        const float* __restrict__ w2, const float* __restrict__ b2,
                        float* __restrict__ tg, float* __restrict__ A, float* __restrict__ B) {
  __shared__ float w1s[64], b1s[64], ts[64];
  __shared__ int rs[64], ms[64], vs[64];
  int tid = threadIdx.x;
  if (tid < 64) {
    float w = w1[tid], b = b1[tid];
    w1s[tid] = w; b1s[tid] = b;
    int v = (w != 0.0f);
    vs[tid] = v;
    ts[tid] = v ? (-b / w) : 0.0f;
  }
  __syncthreads();
  if (tid < 64) {
    float tk = ts[tid];
    int r = 0, m = 0;
    for (int k = 0; k < 64; ++k) if (vs[k]) { r += (ts[k] < tk) ? 1 : 0; m += (ts[k] == tk) ? 1 : 0; }
    rs[tid] = r; ms[tid] = m;
    tg[tid] = vs[tid] ? tk : __builtin_inff();  // +inf: never counted in p
  }
  __syncthreads();
  // piece p is "# thresholds strictly below a". Unit k active at piece p:
  //   w1>0: a>t_k  <=> p >= r_k+m_k ;  w1<0: a<t_k <=> p <= r_k ;  w1==0: b1>0
  // (boundary a==t_k has exactly-zero relu contribution either way)
  for (int idx = tid; idx < 65 * 64; idx += blockDim.x) {
    int p = idx >> 6, j = idx & 63;
    float accA = 0.0f, accB = b2[j];
    for (int k = 0; k < 64; ++k) {
      bool act;
      if (vs[k]) act = (w1s[k] > 0.0f) ? (p >= rs[k] + ms[k]) : (p <= rs[k]);
      else       act = (b1s[k] > 0.0f);
      if (act) { float wv = w2[k * 64 + j]; accA = fmaf(w1s[k], wv, accA); accB = fmaf(b1s[k], wv, accB); }
    }
    A[idx] = accA; B[idx] = accB;
  }
}

__global__ void k_hist(const unsigned int* __restrict__ ei, const int* __restrict__ flag,
                       int* __restrict__ deg, int E) {
  int i = blockIdx.x * blockDim.x + threadIdx.x;
  if (i >= E) return;
  bool is64 = (*flag == 0);
  int dst = is64 ? (int)ei[2 * ((size_t)E + i)] : (int)ei[(size_t)E + i];
  atomicAdd(&deg[dst], 1);
}

__global__ void k_scan1(const int* __restrict__ deg, int* __restrict__ offs,
                        int* __restrict__ bsum, int n) {
  __shared__ int s[256];
  int tx = threadIdx.x;
  int i = blockIdx.x * 256 + tx;
  int v = (i < n) ? deg[i] : 0;
  s[tx] = v;
  __syncthreads();
  for (int d = 1; d < 256; d <<= 1) {
    int add = (tx >= d) ? s[tx - d] : 0;
    __syncthreads();
    s[tx] += add;
    __syncthreads();
  }
  if (i < n) offs[i] = s[tx] - v;           // block-local exclusive
  if (tx == 255) bsum[blockIdx.x] = s[255]; // block total
}

__global__ void k_scan2(int* __restrict__ bsum, int nb) {
  __shared__ int s[512];
  int tx = threadIdx.x;
  int v = (tx < nb) ? bsum[tx] : 0;
  s[tx] = v;
  __syncthreads();
  for (int d = 1; d < 512; d <<= 1) {
    int add = (tx >= d) ? s[tx - d] : 0;
    __syncthreads();
    s[tx] += add;
    __syncthreads();
  }
  if (tx < nb) bsum[tx] = s[tx] - v;        // exclusive block offsets
}

__global__ void k_scan3(int* __restrict__ offs, int* __restrict__ cur,
                        const int* __restrict__ bsum, int n, int Etot) {
  int i = blockIdx.x * 256 + threadIdx.x;
  if (i < n) { int o = offs[i] + bsum[blockIdx.x]; offs[i] = o; cur[i] = o; }
  if (blockIdx.x == 0 && threadIdx.x == 0) offs[n] = Etot;
}

__global__ void k_scatter(const unsigned int* __restrict__ ei, const float* __restrict__ ea_in,
                          const int* __restrict__ flag, const float* __restrict__ tg,
                          int* __restrict__ cur, int* __restrict__ srcp,
                          float* __restrict__ ea_out, int E) {
  __shared__ float ts[64];
  if (threadIdx.x < 64) ts[threadIdx.x] = tg[threadIdx.x];
  __syncthreads();
  int i = blockIdx.x * blockDim.x + threadIdx.x;
  if (i >= E) return;
  bool is64 = (*flag == 0);
  int src, dst;
  if (is64) { src = (int)ei[2 * (size_t)i]; dst = (int)ei[2 * ((size_t)E + i)]; }
  else      { src = (int)ei[(size_t)i];     dst = (int)ei[(size_t)E + i]; }
  float a = ea_in[i];
  int p = 0;
#pragma unroll
  for (int k = 0; k < 64; ++k) p += (ts[k] < a) ? 1 : 0;
  int pos = atomicAdd(&cur[dst], 1);
  srcp[pos] = src | (p << 20);   // src < 2^20, p <= 64
  ea_out[pos] = a;
}

__global__ __launch_bounds__(256) void k_conv(
    const float* __restrict__ xin, const int* __restrict__ offs,
    const int* __restrict__ srcp, const float* __restrict__ ea,
    const float* __restrict__ Ag, const float* __restrict__ Bg,
    const float* __restrict__ epsp, float* __restrict__ uout, int n) {
  __shared__ float As[65 * 64], Bs[65 * 64];
  {
    const float4* A4 = (const float4*)Ag; const float4* B4 = (const float4*)Bg;
    float4* As4 = (float4*)As; float4* Bs4 = (float4*)Bs;
    for (int i = threadIdx.x; i < 65 * 16; i += 256) { As4[i] = A4[i]; Bs4[i] = B4[i]; }
  }
  __syncthreads();
  const int lane = threadIdx.x & 63;
  const int wid = threadIdx.x >> 6;
  const float scale = 1.0f + epsp[0];
  for (int node = blockIdx.x * 4 + wid; node < n; node += gridDim.x * 4) {
    int s = offs[node], e = offs[node + 1];
    float acc = 0.0f;
    int i = s;
    for (; i + 1 < e; i += 2) {  // 2-wide unroll: independent gathers in flight
      int sp0 = srcp[i], sp1 = srcp[i + 1];
      float a0 = ea[i], a1 = ea[i + 1];
      int s0 = sp0 & 0xFFFFF, p0 = sp0 >> 20;
      int s1 = sp1 & 0xFFFFF, p1 = sp1 >> 20;
      float x0 = xin[(size_t)s0 * 64 + lane];
      float x1 = xin[(size_t)s1 * 64 + lane];
      float e0 = fmaf(a0, As[p0 * 64 + lane], Bs[p0 * 64 + lane]);
      float e1 = fmaf(a1, As[p1 * 64 + lane], Bs[p1 * 64 + lane]);
      acc += fmaxf(x0 + e0, 0.0f);
      acc += fmaxf(x1 + e1, 0.0f);
    }
    if (i < e) {
      int sp0 = srcp[i]; float a0 = ea[i];
      int s0 = sp0 & 0xFFFFF, p0 = sp0 >> 20;
      float x0 = xin[(size_t)s0 * 64 + lane];
      float e0 = fmaf(a0, As[p0 * 64 + lane], Bs[p0 * 64 + lane]);
      acc += fmaxf(x0 + e0, 0.0f);
    }
    uout[(size_t)node * 64 + lane] = fmaf(scale, xin[(size_t)node * 64 + lane], acc);
  }
}

// thread-per-node MLP; u rows in LDS (stride 65 -> conflict-free), 64 reg accumulators,
// weights read wave-uniform (scalar-cache / L1-hot). Writes relu(mlp(u)).
__global__ __launch_bounds__(128) void k_mlp(
    const float* __restrict__ uin, float* __restrict__ hout,
    const float* __restrict__ W1, const float* __restrict__ B1,
    const float* __restrict__ W2, const float* __restrict__ B2, int n) {
  __shared__ float row[128 * 65];
  const int tid = threadIdx.x;
  const size_t base = (size_t)blockIdx.x * 128 * 64;
  for (int k = 0; k < 64; ++k) {               // coalesced load -> padded LDS rows
    int f = k * 128 + tid;
    row[(f >> 6) * 65 + (f & 63)] = uin[base + f];
  }
  __syncthreads();
  float* r = &row[tid * 65];
  float h1[64];
#pragma unroll
  for (int i = 0; i < 64; ++i) h1[i] = B1[i];
  for (int j = 0; j < 64; ++j) {
    float uj = r[j];
    const float* wr = &W1[j * 64];
#pragma unroll
    for (int i = 0; i < 64; ++i) h1[i] = fmaf(uj, wr[i], h1[i]);
  }
#pragma unroll
  for (int i = 0; i < 64; ++i) r[i] = fmaxf(h1[i], 0.0f);  // own row: no sync needed
  float h2[64];
#pragma unroll
  for (int i = 0; i < 64; ++i) h2[i] = B2[i];
  for (int j = 0; j < 64; ++j) {
    float uj = r[j];
    const float* wr = &W2[j * 64];
#pragma unroll
    for (int i = 0; i < 64; ++i) h2[i] = fmaf(uj, wr[i], h2[i]);
  }
#pragma unroll
  for (int i = 0; i < 64; ++i) r[i] = fmaxf(h2[i], 0.0f);
  __syncthreads();
  for (int k = 0; k < 64; ++k) {               // coalesced store
    int f = k * 128 + tid;
    hout[base + f] = row[(f >> 6) * 65 + (f & 63)];
  }
}

__global__ __launch_bounds__(128) void k_classify(
    const float* __restrict__ hin, const float* __restrict__ LW,
    const float* __restrict__ LB, float* __restrict__ out, int n) {
  __shared__ float row[128 * 65];
  const int tid = threadIdx.x;
  const size_t base = (size_t)blockIdx.x * 128 * 64;
  for (int k = 0; k < 64; ++k) {
    int f = k * 128 + tid;
    row[(f >> 6) * 65 + (f & 63)] = hin[base + f];
  }
  __syncthreads();
  int node = blockIdx.x * 128 + tid;
  float lg[40];
#pragma unroll
  for (int c = 0; c < 40; ++c) lg[c] = LB[c];
  const float* r = &row[tid * 65];
  for (int j = 0; j < 64; ++j) {
    float hj = r[j];
    const float* w = &LW[j * 40];
#pragma unroll
    for (int c = 0; c < 40; ++c) lg[c] = fmaf(hj, w[c], lg[c]);
  }
  if (node < n) {
    float mx = lg[0];
#pragma unroll
    for (int c = 1; c < 40; ++c) mx = fmaxf(mx, lg[c]);
    float se = 0.0f;
#pragma unroll
    for (int c = 0; c < 40; ++c) se += __expf(lg[c] - mx);
    float lse = mx + __logf(se);
    float* o = out + (size_t)node * 40;
#pragma unroll
    for (int q = 0; q < 10; ++q) {
      float4 v = make_float4(lg[q * 4] - lse, lg[q * 4 + 1] - lse,
                             lg[q * 4 + 2] - lse, lg[q * 4 + 3] - lse);
      *(float4*)(o + q * 4) = v;
    }
  }
}

extern "C" void kernel_launch(void* const* d_in, const int* in_sizes, int n_in,
                              void* d_out, int out_size, void* d_ws, size_t ws_size,
                              hipStream_t stream) {
  (void)n_in; (void)out_size; (void)ws_size;
  const float* x        = (const float*)d_in[0];
  const unsigned int* ei = (const unsigned int*)d_in[1];
  const float* eattr    = (const float*)d_in[2];
  const float* e_w1 = (const float*)d_in[3];
  const float* e_b1 = (const float*)d_in[4];
  const float* e_w2 = (const float*)d_in[5];
  const float* e_b2 = (const float*)d_in[6];
  const float* eps1 = (const float*)d_in[7];
  const float* m1w1 = (const float*)d_in[8];
  const float* m1b1 = (const float*)d_in[9];
  const float* m1w2 = (const float*)d_in[10];
  const float* m1b2 = (const float*)d_in[11];
  const float* eps2 = (const float*)d_in[12];
  const float* m2w1 = (const float*)d_in[13];
  const float* m2b1 = (const float*)d_in[14];
  const float* m2w2 = (const float*)d_in[15];
  const float* m2b2 = (const float*)d_in[16];
  const float* linw = (const float*)d_in[17];
  const float* linb = (const float*)d_in[18];

  const int N = in_sizes[0] / 64;
  const int E = in_sizes[1] / 2;

  char* ws = (char*)d_ws;
  size_t off = 0;
  auto alloc = [&](size_t bytes, size_t align) {
    off = (off + align - 1) & ~(align - 1);
    size_t r = off; off += bytes; return r;
  };
  size_t oFlag = alloc(64, 64);
  size_t oT    = alloc(64 * 4, 64);
  size_t oA    = alloc(65 * 64 * 4, 64);
  size_t oB    = alloc(65 * 64 * 4, 64);
  size_t oDeg  = alloc((size_t)N * 4, 128);
  size_t oOffs = alloc(((size_t)N + 1) * 4, 128);
  size_t oCur  = alloc((size_t)N * 4, 128);
  size_t oBsum = alloc(512 * 4, 128);
  size_t oSrcP = alloc((size_t)E * 4, 128);
  size_t oEa   = alloc((size_t)E * 4, 128);
  size_t oU    = alloc((size_t)N * 64 * 4 + 65536, 1024); // +pad: tail blocks read past N
  size_t oH    = alloc((size_t)N * 64 * 4 + 65536, 1024);

  int*   flag = (int*)(ws + oFlag);
  float* t    = (float*)(ws + oT);
  float* A    = (float*)(ws + oA);
  float* B    = (float*)(ws + oB);
  int*   deg  = (int*)(ws + oDeg);
  int*   offs = (int*)(ws + oOffs);
  int*   cur  = (int*)(ws + oCur);
  int*   bsum = (int*)(ws + oBsum);
  int*   srcp = (int*)(ws + oSrcP);
  float* eaw  = (float*)(ws + oEa);
  float* ubuf = (float*)(ws + oU);
  float* hbuf = (float*)(ws + oH);

  hipMemsetAsync(ws + oFlag, 0, 64, stream);
  hipMemsetAsync(ws + oDeg, 0, (size_t)N * 4, stream);

  const int EB = (E + 255) / 256;
  const int NB = (N + 255) / 256;
  const int MB = (N + 127) / 128;

  k_detect<<<EB, 256, 0, stream>>>(ei, flag, E);
  k_setup<<<1, 256, 0, stream>>>(e_w1, e_b1, e_w2, e_b2, t, A, B);
  k_hist<<<EB, 256, 0, stream>>>(ei, flag, deg, E);
  k_scan1<<<NB, 256, 0, stream>>>(deg, offs, bsum, N);
  k_scan2<<<1, 512, 0, stream>>>(bsum, NB);
  k_scan3<<<NB, 256, 0, stream>>>(offs, cur, bsum, N, E);
  k_scatter<<<EB, 256, 0, stream>>>(ei, eattr, flag, t, cur, srcp, eaw, E);
  k_conv<<<2048, 256, 0, stream>>>(x, offs, srcp, eaw, A, B, eps1, ubuf, N);
  k_mlp<<<MB, 128, 0, stream>>>(ubuf, hbuf, m1w1, m1b1, m1w2, m1b2, N);
  k_conv<<<2048, 256, 0, stream>>>(hbuf, offs, srcp, eaw, A, B, eps2, ubuf, N);
  k_mlp<<<MB, 128, 0, stream>>>(ubuf, hbuf, m2w1, m2b1, m2w2, m2b2, N);
  k_classify<<<MB, 128, 0, stream>>>(hbuf, linw, linb, (float*)d_out, N);
}

// Round 2
// 837.200 us; speedup vs baseline: 1.4380x; 1.4380x over previous
//
#include <hip/hip_runtime.h>
#include <hip/hip_bf16.h>
#include <stdint.h>

// GINE net, MI355X. Pipeline:
//   k_detect  : int32-vs-int64 width detection, SAMPLED (1 block, <=4 atomics; R0's
//               full-scan version cost 286us on same-address atomicOr contention)
//   k_setup   : piecewise-linear edge-MLP coeffs AB[65][64] (float2 A,B), thresholds t[64]
//   k_cast    : f32 -> bf16 copy of node features (halves gather line traffic in k_conv)
//   k_hist/scan1/scan2/scan3/k_scatter : CSR build by dst; payload int2{src|p<<20, a}
//   k_conv    : u = (1+eps)*x + sum relu(bf16(x[src]) + a*A_p + B_p), atomic-free, 4-wide
//   k_mlp     : node MLP, thread-per-node, LDS rows (stride 65); writes f32 + bf16 copies
//   k_classify: logits + log_softmax

typedef unsigned int uint32;
typedef unsigned short ushort16;

static __device__ __forceinline__ unsigned short f2bf(float f) {
  __hip_bfloat16 h = __float2bfloat16(f);
  return *reinterpret_cast<unsigned short*>(&h);
}
static __device__ __forceinline__ float bf2f(unsigned short u) {
  return __uint_as_float(((uint32)u) << 16);
}

// Sampled width detection: odd 32-bit words among the first 2E words are src values
// (int32 layout, ~all nonzero) or int64 high-halves (all zero since idx < 2^20).
__global__ void k_detect(const uint32* __restrict__ w, int* __restrict__ flag, int E) {
  int cnt = (E < 4096) ? E : 4096;
  int nz = 0;
  for (int i = threadIdx.x; i < cnt; i += 256) nz |= (w[2 * (size_t)i + 1] != 0u);
  if (__any(nz) && (threadIdx.x & 63) == 0) atomicOr(flag, 1);
}

__global__ void k_setup(const float* __restrict__ w1, const float* __restrict__ b1,
                        const float* __restrict__ w2, const float* __restrict__ b2,
                        float* __restrict__ tg, float2* __restrict__ AB) {
  __shared__ float w1s[64], b1s[64], ts[64];
  __shared__ int rs[64], ms[64], vs[64];
  int tid = threadIdx.x;
  if (tid < 64) {
    float w = w1[tid], b = b1[tid];
    w1s[tid] = w; b1s[tid] = b;
    int v = (w != 0.0f);
    vs[tid] = v;
    ts[tid] = v ? (-b / w) : 0.0f;
  }
  __syncthreads();
  if (tid < 64) {
    float tk = ts[tid];
    int r = 0, m = 0;
    for (int k = 0; k < 64; ++k) if (vs[k]) { r += (ts[k] < tk) ? 1 : 0; m += (ts[k] == tk) ? 1 : 0; }
    rs[tid] = r; ms[tid] = m;
    tg[tid] = vs[tid] ? tk : __builtin_inff();  // +inf: never counted in p
  }
  __syncthreads();
  // piece p = #{thresholds strictly below a}. Unit k active at piece p:
  //   w1>0: p >= r_k+m_k ; w1<0: p <= r_k ; w1==0: b1>0
  for (int idx = tid; idx < 65 * 64; idx += blockDim.x) {
    int p = idx >> 6, j = idx & 63;
    float accA = 0.0f, accB = b2[j];
    for (int k = 0; k < 64; ++k) {
      bool act;
      if (vs[k]) act = (w1s[k] > 0.0f) ? (p >= rs[k] + ms[k]) : (p <= rs[k]);
      else       act = (b1s[k] > 0.0f);
      if (act) { float wv = w2[k * 64 + j]; accA = fmaf(w1s[k], wv, accA); accB = fmaf(b1s[k], wv, accB); }
    }
    AB[idx] = make_float2(accA, accB);
  }
}

__global__ void k_cast(const float* __restrict__ in, ushort16* __restrict__ out, int n4) {
  int i = blockIdx.x * blockDim.x + threadIdx.x;
  if (i >= n4) return;
  float4 v = ((const float4*)in)[i];
  ushort4 o;
  o.x = f2bf(v.x); o.y = f2bf(v.y); o.z = f2bf(v.z); o.w = f2bf(v.w);
  ((ushort4*)out)[i] = o;
}

__global__ void k_hist(const uint32* __restrict__ ei, const int* __restrict__ flag,
                       int* __restrict__ deg, int E) {
  int i = blockIdx.x * blockDim.x + threadIdx.x;
  if (i >= E) return;
  bool is64 = (*flag == 0);
  int dst = is64 ? (int)ei[2 * ((size_t)E + i)] : (int)ei[(size_t)E + i];
  atomicAdd(&deg[dst], 1);
}

__global__ void k_scan1(const int* __restrict__ deg, int* __restrict__ offs,
                        int* __restrict__ bsum, int n) {
  __shared__ int s[256];
  int tx = threadIdx.x;
  int i = blockIdx.x * 256 + tx;
  int v = (i < n) ? deg[i] : 0;
  s[tx] = v;
  __syncthreads();
  for (int d = 1; d < 256; d <<= 1) {
    int add = (tx >= d) ? s[tx - d] : 0;
    __syncthreads();
    s[tx] += add;
    __syncthreads();
  }
  if (i < n) offs[i] = s[tx] - v;
  if (tx == 255) bsum[blockIdx.x] = s[255];
}

__global__ void k_scan2(int* __restrict__ bsum, int nb) {
  __shared__ int s[512];
  int tx = threadIdx.x;
  int v = (tx < nb) ? bsum[tx] : 0;
  s[tx] = v;
  __syncthreads();
  for (int d = 1; d < 512; d <<= 1) {
    int add = (tx >= d) ? s[tx - d] : 0;
    __syncthreads();
    s[tx] += add;
    __syncthreads();
  }
  if (tx < nb) bsum[tx] = s[tx] - v;
}

__global__ void k_scan3(int* __restrict__ offs, int* __restrict__ cur,
                        const int* __restrict__ bsum, int n, int Etot) {
  int i = blockIdx.x * 256 + threadIdx.x;
  if (i < n) { int o = offs[i] + bsum[blockIdx.x]; offs[i] = o; cur[i] = o; }
  if (blockIdx.x == 0 && threadIdx.x == 0) offs[n] = Etot;
}

__global__ void k_scatter(const uint32* __restrict__ ei, const float* __restrict__ ea_in,
                          const int* __restrict__ flag, const float* __restrict__ tg,
                          int* __restrict__ cur, int2* __restrict__ pay, int E) {
  __shared__ float ts[64];
  if (threadIdx.x < 64) ts[threadIdx.x] = tg[threadIdx.x];
  __syncthreads();
  int i = blockIdx.x * blockDim.x + threadIdx.x;
  if (i >= E) return;
  bool is64 = (*flag == 0);
  int src, dst;
  if (is64) { src = (int)ei[2 * (size_t)i]; dst = (int)ei[2 * ((size_t)E + i)]; }
  else      { src = (int)ei[(size_t)i];     dst = (int)ei[(size_t)E + i]; }
  float a = ea_in[i];
  int p = 0;
#pragma unroll
  for (int k = 0; k < 64; ++k) p += (ts[k] < a) ? 1 : 0;
  int pos = atomicAdd(&cur[dst], 1);
  int2 v; v.x = src | (p << 20); v.y = __float_as_int(a);  // src < 2^20, p <= 64
  pay[pos] = v;
}

__global__ __launch_bounds__(256) void k_conv(
    const float* __restrict__ xin, const ushort16* __restrict__ xb,
    const int* __restrict__ offs, const int2* __restrict__ pay,
    const float2* __restrict__ ABg, const float* __restrict__ epsp,
    float* __restrict__ uout, int n) {
  __shared__ float2 ABs[65 * 64];  // 33280 B -> 4 blocks/CU
  {
    const float4* g4 = (const float4*)ABg;
    float4* s4 = (float4*)ABs;
    for (int i = threadIdx.x; i < 65 * 32; i += 256) s4[i] = g4[i];
  }
  __syncthreads();
  const int lane = threadIdx.x & 63;
  const int wid = threadIdx.x >> 6;
  const float scale = 1.0f + epsp[0];
  for (int node = blockIdx.x * 4 + wid; node < n; node += gridDim.x * 4) {
    int s = offs[node], e = offs[node + 1];
    float acc = 0.0f;
    int i = s;
    for (; i + 3 < e; i += 4) {  // 4 gathers in flight
      int2 q0 = pay[i], q1 = pay[i + 1], q2 = pay[i + 2], q3 = pay[i + 3];
      int s0 = q0.x & 0xFFFFF, p0 = (uint32)q0.x >> 20;
      int s1 = q1.x & 0xFFFFF, p1 = (uint32)q1.x >> 20;
      int s2 = q2.x & 0xFFFFF, p2 = (uint32)q2.x >> 20;
      int s3 = q3.x & 0xFFFFF, p3 = (uint32)q3.x >> 20;
      float x0 = bf2f(xb[(size_t)s0 * 64 + lane]);
      float x1 = bf2f(xb[(size_t)s1 * 64 + lane]);
      float x2 = bf2f(xb[(size_t)s2 * 64 + lane]);
      float x3 = bf2f(xb[(size_t)s3 * 64 + lane]);
      float2 ab0 = ABs[p0 * 64 + lane];
      float2 ab1 = ABs[p1 * 64 + lane];
      float2 ab2 = ABs[p2 * 64 + lane];
      float2 ab3 = ABs[p3 * 64 + lane];
      acc += fmaxf(fmaf(__int_as_float(q0.y), ab0.x, ab0.y) + x0, 0.0f);
      acc += fmaxf(fmaf(__int_as_float(q1.y), ab1.x, ab1.y) + x1, 0.0f);
      acc += fmaxf(fmaf(__int_as_float(q2.y), ab2.x, ab2.y) + x2, 0.0f);
      acc += fmaxf(fmaf(__int_as_float(q3.y), ab3.x, ab3.y) + x3, 0.0f);
    }
    for (; i < e; ++i) {
      int2 q0 = pay[i];
      int s0 = q0.x & 0xFFFFF, p0 = (uint32)q0.x >> 20;
      float x0 = bf2f(xb[(size_t)s0 * 64 + lane]);
      float2 ab0 = ABs[p0 * 64 + lane];
      acc += fmaxf(fmaf(__int_as_float(q0.y), ab0.x, ab0.y) + x0, 0.0f);
    }
    uout[(size_t)node * 64 + lane] = fmaf(scale, xin[(size_t)node * 64 + lane], acc);
  }
}

// thread-per-node MLP; u rows in LDS (stride 65 -> conflict-free), 64 reg accumulators,
// weights read wave-uniform (L1-hot broadcasts). Writes relu(mlp(u)) as f32 AND bf16.
__global__ __launch_bounds__(128) void k_mlp(
    const float* __restrict__ uin, float* __restrict__ hout, ushort16* __restrict__ houtb,
    const float* __restrict__ W1, const float* __restrict__ B1,
    const float* __restrict__ W2, const float* __restrict__ B2, int n) {
  __shared__ float row[128 * 65];
  const int tid = threadIdx.x;
  const size_t base = (size_t)blockIdx.x * 128 * 64;
  for (int k = 0; k < 64; ++k) {
    int f = k * 128 + tid;
    row[(f >> 6) * 65 + (f & 63)] = uin[base + f];
  }
  __syncthreads();
  float* r = &row[tid * 65];
  float h1[64];
#pragma unroll
  for (int i = 0; i < 64; ++i) h1[i] = B1[i];
  for (int j = 0; j < 64; ++j) {
    float uj = r[j];
    const float* wr = &W1[j * 64];
#pragma unroll
    for (int i = 0; i < 64; ++i) h1[i] = fmaf(uj, wr[i], h1[i]);
  }
#pragma unroll
  for (int i = 0; i < 64; ++i) r[i] = fmaxf(h1[i], 0.0f);  // own row: no sync needed
  float h2[64];
#pragma unroll
  for (int i = 0; i < 64; ++i) h2[i] = B2[i];
  for (int j = 0; j < 64; ++j) {
    float uj = r[j];
    const float* wr = &W2[j * 64];
#pragma unroll
    for (int i = 0; i < 64; ++i) h2[i] = fmaf(uj, wr[i], h2[i]);
  }
#pragma unroll
  for (int i = 0; i < 64; ++i) r[i] = fmaxf(h2[i], 0.0f);
  __syncthreads();
  for (int k = 0; k < 64; ++k) {
    int f = k * 128 + tid;
    hout[base + f] = row[(f >> 6) * 65 + (f & 63)];
  }
  // bf16 copy, coalesced 4B stores (2 features/thread/iter; pairs never straddle rows)
  uint32* ob = (uint32*)houtb;
  for (int k = 0; k < 32; ++k) {
    int f = k * 256 + tid * 2;
    uint32 lo = f2bf(row[(f >> 6) * 65 + (f & 63)]);
    uint32 hi = f2bf(row[(f >> 6) * 65 + ((f & 63) + 1)]);
    ob[(base + f) >> 1] = lo | (hi << 16);
  }
}

__global__ __launch_bounds__(128) void k_classify(
    const float* __restrict__ hin, const float* __restrict__ LW,
    const float* __restrict__ LB, float* __restrict__ out, int n) {
  __shared__ float row[128 * 65];
  const int tid = threadIdx.x;
  const size_t base = (size_t)blockIdx.x * 128 * 64;
  for (int k = 0; k < 64; ++k) {
    int f = k * 128 + tid;
    row[(f >> 6) * 65 + (f & 63)] = hin[base + f];
  }
  __syncthreads();
  int node = blockIdx.x * 128 + tid;
  float lg[40];
#pragma unroll
  for (int c = 0; c < 40; ++c) lg[c] = LB[c];
  const float* r = &row[tid * 65];
  for (int j = 0; j < 64; ++j) {
    float hj = r[j];
    const float* w = &LW[j * 40];
#pragma unroll
    for (int c = 0; c < 40; ++c) lg[c] = fmaf(hj, w[c], lg[c]);
  }
  if (node < n) {
    float mx = lg[0];
#pragma unroll
    for (int c = 1; c < 40; ++c) mx = fmaxf(mx, lg[c]);
    float se = 0.0f;
#pragma unroll
    for (int c = 0; c < 40; ++c) se += __expf(lg[c] - mx);
    float lse = mx + __logf(se);
    float* o = out + (size_t)node * 40;
#pragma unroll
    for (int q = 0; q < 10; ++q) {
      float4 v = make_float4(lg[q * 4] - lse, lg[q * 4 + 1] - lse,
                             lg[q * 4 + 2] - lse, lg[q * 4 + 3] - lse);
      *(float4*)(o + q * 4) = v;
    }
  }
}

extern "C" void kernel_launch(void* const* d_in, const int* in_sizes, int n_in,
                              void* d_out, int out_size, void* d_ws, size_t ws_size,
                              hipStream_t stream) {
  (void)n_in; (void)out_size; (void)ws_size;
  const float* x         = (const float*)d_in[0];
  const uint32* ei       = (const uint32*)d_in[1];
  const float* eattr     = (const float*)d_in[2];
  const float* e_w1 = (const float*)d_in[3];
  const float* e_b1 = (const float*)d_in[4];
  const float* e_w2 = (const float*)d_in[5];
  const float* e_b2 = (const float*)d_in[6];
  const float* eps1 = (const float*)d_in[7];
  const float* m1w1 = (const float*)d_in[8];
  const float* m1b1 = (const float*)d_in[9];
  const float* m1w2 = (const float*)d_in[10];
  const float* m1b2 = (const float*)d_in[11];
  const float* eps2 = (const float*)d_in[12];
  const float* m2w1 = (const float*)d_in[13];
  const float* m2b1 = (const float*)d_in[14];
  const float* m2w2 = (const float*)d_in[15];
  const float* m2b2 = (const float*)d_in[16];
  const float* linw = (const float*)d_in[17];
  const float* linb = (const float*)d_in[18];

  const int N = in_sizes[0] / 64;
  const int E = in_sizes[1] / 2;

  char* ws = (char*)d_ws;
  size_t off = 0;
  auto alloc = [&](size_t bytes, size_t align) {
    off = (off + align - 1) & ~(align - 1);
    size_t r = off; off += bytes; return r;
  };
  size_t oFlag = alloc(64, 64);
  size_t oT    = alloc(64 * 4, 64);
  size_t oAB   = alloc(65 * 64 * 8, 64);
  size_t oDeg  = alloc((size_t)N * 4, 128);
  size_t oOffs = alloc(((size_t)N + 1) * 4, 128);
  size_t oCur  = alloc((size_t)N * 4, 128);
  size_t oBsum = alloc(512 * 4, 128);
  size_t oPay  = alloc((size_t)E * 8, 256);
  size_t oXb   = alloc((size_t)N * 64 * 2 + 32768, 256);  // bf16 gather table (+tail pad)
  size_t oU    = alloc((size_t)N * 64 * 4 + 65536, 1024); // +pad: tail blocks read past N
  size_t oH    = alloc((size_t)N * 64 * 4 + 65536, 1024);

  int*    flag = (int*)(ws + oFlag);
  float*  t    = (float*)(ws + oT);
  float2* AB   = (float2*)(ws + oAB);
  int*    deg  = (int*)(ws + oDeg);
  int*    offs = (int*)(ws + oOffs);
  int*    cur  = (int*)(ws + oCur);
  int*    bsum = (int*)(ws + oBsum);
  int2*   pay  = (int2*)(ws + oPay);
  ushort16* xb = (ushort16*)(ws + oXb);
  float*  ubuf = (float*)(ws + oU);
  float*  hbuf = (float*)(ws + oH);

  hipMemsetAsync(ws + oFlag, 0, 64, stream);
  hipMemsetAsync(ws + oDeg, 0, (size_t)N * 4, stream);

  const int EB = (E + 255) / 256;
  const int NB = (N + 255) / 256;
  const int MB = (N + 127) / 128;
  const int CB = (N * 64 / 4 + 255) / 256;

  k_detect<<<1, 256, 0, stream>>>(ei, flag, E);
  k_setup<<<1, 256, 0, stream>>>(e_w1, e_b1, e_w2, e_b2, t, AB);
  k_cast<<<CB, 256, 0, stream>>>(x, xb, N * 64 / 4);
  k_hist<<<EB, 256, 0, stream>>>(ei, flag, deg, E);
  k_scan1<<<NB, 256, 0, stream>>>(deg, offs, bsum, N);
  k_scan2<<<1, 512, 0, stream>>>(bsum, NB);
  k_scan3<<<NB, 256, 0, stream>>>(offs, cur, bsum, N, E);
  k_scatter<<<EB, 256, 0, stream>>>(ei, eattr, flag, t, cur, pay, E);
  k_conv<<<2048, 256, 0, stream>>>(x, xb, offs, pay, AB, eps1, ubuf, N);
  k_mlp<<<MB, 128, 0, stream>>>(ubuf, hbuf, xb, m1w1, m1b1, m1w2, m1b2, N);
  k_conv<<<2048, 256, 0, stream>>>(hbuf, xb, offs, pay, AB, eps2, ubuf, N);
  k_mlp<<<MB, 128, 0, stream>>>(ubuf, hbuf, xb, m2w1, m2b1, m2w2, m2b2, N);
  k_classify<<<MB, 128, 0, stream>>>(hbuf, linw, linb, (float*)d_out, N);
}

// Round 3
// 668.650 us; speedup vs baseline: 1.8004x; 1.2521x over previous
//
#include <hip/hip_runtime.h>
#include <hip/hip_bf16.h>
#include <stdint.h>

// GINE net, MI355X. Pipeline:
//   k_detect  : int32-vs-int64 width detection, SAMPLED (1 block, <=4 atomics)
//   k_setup   : piecewise-linear edge-MLP coeffs AB[65][64] (float2 A,B), thresholds t[64]
//               R2: 65 blocks (one per piece), w2 staged in LDS -- R1's single-block
//               version was 180us of serialized cold global loads on one CU.
//   k_cast    : f32 -> bf16 copy of node features (halves gather line traffic in k_conv)
//   k_hist/scan1/scan2/scan3/k_scatter : CSR build by dst; payload int2{src|p<<20, a}
//   k_conv    : u = (1+eps)*x + sum relu(bf16(x[src]) + a*A_p + B_p), atomic-free, 4-wide
//   k_mlp     : node MLP, thread-per-node, LDS rows (stride 65); writes f32 + bf16 copies
//   k_classify: logits + log_softmax

typedef unsigned int uint32;
typedef unsigned short ushort16;

static __device__ __forceinline__ unsigned short f2bf(float f) {
  __hip_bfloat16 h = __float2bfloat16(f);
  return *reinterpret_cast<unsigned short*>(&h);
}
static __device__ __forceinline__ float bf2f(unsigned short u) {
  return __uint_as_float(((uint32)u) << 16);
}

// Sampled width detection: odd 32-bit words among the first 2E words are src values
// (int32 layout, ~all nonzero) or int64 high-halves (all zero since idx < 2^20).
__global__ void k_detect(const uint32* __restrict__ w, int* __restrict__ flag, int E) {
  int cnt = (E < 4096) ? E : 4096;
  int nz = 0;
  for (int i = threadIdx.x; i < cnt; i += 256) nz |= (w[2 * (size_t)i + 1] != 0u);
  if (__any(nz) && (threadIdx.x & 63) == 0) atomicOr(flag, 1);
}

// One block per piece p (65 blocks). w2/b2 staged in LDS; threshold metadata
// recomputed per block (64 values, trivial).
__global__ __launch_bounds__(256) void k_setup(
    const float* __restrict__ w1, const float* __restrict__ b1,
    const float* __restrict__ w2, const float* __restrict__ b2,
    float* __restrict__ tg, float2* __restrict__ AB) {
  __shared__ float w2s[64 * 64];   // 16 KB
  __shared__ float b2s[64];
  __shared__ float w1s[64], b1s[64], ts[64];
  __shared__ int rs[64], ms[64], vs[64];
  const int tid = threadIdx.x;
  const int p = blockIdx.x;

  // stage w2 (coalesced float4) + b2
  {
    const float4* g4 = (const float4*)w2;
    float4* s4 = (float4*)w2s;
    for (int i = tid; i < 64 * 16; i += 256) s4[i] = g4[i];
    if (tid < 64) b2s[tid] = b2[tid];
  }
  if (tid < 64) {
    float w = w1[tid], b = b1[tid];
    w1s[tid] = w; b1s[tid] = b;
    int v = (w != 0.0f);
    vs[tid] = v;
    ts[tid] = v ? (-b / w) : 0.0f;
  }
  __syncthreads();
  if (tid < 64) {
    float tk = ts[tid];
    int r = 0, m = 0;
    for (int k = 0; k < 64; ++k) if (vs[k]) { r += (ts[k] < tk) ? 1 : 0; m += (ts[k] == tk) ? 1 : 0; }
    rs[tid] = r; ms[tid] = m;
    if (p == 0) tg[tid] = vs[tid] ? tk : __builtin_inff();  // +inf: never counted in p
  }
  __syncthreads();
  // piece p = #{thresholds strictly below a}. Unit k active at piece p:
  //   w1>0: p >= r_k+m_k ; w1<0: p <= r_k ; w1==0: b1>0
  if (tid < 64) {
    const int j = tid;
    float accA = 0.0f, accB = b2s[j];
    for (int k = 0; k < 64; ++k) {
      bool act;
      if (vs[k]) act = (w1s[k] > 0.0f) ? (p >= rs[k] + ms[k]) : (p <= rs[k]);
      else       act = (b1s[k] > 0.0f);
      if (act) { float wv = w2s[k * 64 + j]; accA = fmaf(w1s[k], wv, accA); accB = fmaf(b1s[k], wv, accB); }
    }
    AB[p * 64 + j] = make_float2(accA, accB);
  }
}

__global__ void k_cast(const float* __restrict__ in, ushort16* __restrict__ out, int n4) {
  int i = blockIdx.x * blockDim.x + threadIdx.x;
  if (i >= n4) return;
  float4 v = ((const float4*)in)[i];
  ushort4 o;
  o.x = f2bf(v.x); o.y = f2bf(v.y); o.z = f2bf(v.z); o.w = f2bf(v.w);
  ((ushort4*)out)[i] = o;
}

__global__ void k_hist(const uint32* __restrict__ ei, const int* __restrict__ flag,
                       int* __restrict__ deg, int E) {
  int i = blockIdx.x * blockDim.x + threadIdx.x;
  if (i >= E) return;
  bool is64 = (*flag == 0);
  int dst = is64 ? (int)ei[2 * ((size_t)E + i)] : (int)ei[(size_t)E + i];
  atomicAdd(&deg[dst], 1);
}

__global__ void k_scan1(const int* __restrict__ deg, int* __restrict__ offs,
                        int* __restrict__ bsum, int n) {
  __shared__ int s[256];
  int tx = threadIdx.x;
  int i = blockIdx.x * 256 + tx;
  int v = (i < n) ? deg[i] : 0;
  s[tx] = v;
  __syncthreads();
  for (int d = 1; d < 256; d <<= 1) {
    int add = (tx >= d) ? s[tx - d] : 0;
    __syncthreads();
    s[tx] += add;
    __syncthreads();
  }
  if (i < n) offs[i] = s[tx] - v;
  if (tx == 255) bsum[blockIdx.x] = s[255];
}

__global__ void k_scan2(int* __restrict__ bsum, int nb) {
  __shared__ int s[512];
  int tx = threadIdx.x;
  int v = (tx < nb) ? bsum[tx] : 0;
  s[tx] = v;
  __syncthreads();
  for (int d = 1; d < 512; d <<= 1) {
    int add = (tx >= d) ? s[tx - d] : 0;
    __syncthreads();
    s[tx] += add;
    __syncthreads();
  }
  if (tx < nb) bsum[tx] = s[tx] - v;
}

__global__ void k_scan3(int* __restrict__ offs, int* __restrict__ cur,
                        const int* __restrict__ bsum, int n, int Etot) {
  int i = blockIdx.x * 256 + threadIdx.x;
  if (i < n) { int o = offs[i] + bsum[blockIdx.x]; offs[i] = o; cur[i] = o; }
  if (blockIdx.x == 0 && threadIdx.x == 0) offs[n] = Etot;
}

__global__ void k_scatter(const uint32* __restrict__ ei, const float* __restrict__ ea_in,
                          const int* __restrict__ flag, const float* __restrict__ tg,
                          int* __restrict__ cur, int2* __restrict__ pay, int E) {
  __shared__ float ts[64];
  if (threadIdx.x < 64) ts[threadIdx.x] = tg[threadIdx.x];
  __syncthreads();
  int i = blockIdx.x * blockDim.x + threadIdx.x;
  if (i >= E) return;
  bool is64 = (*flag == 0);
  int src, dst;
  if (is64) { src = (int)ei[2 * (size_t)i]; dst = (int)ei[2 * ((size_t)E + i)]; }
  else      { src = (int)ei[(size_t)i];     dst = (int)ei[(size_t)E + i]; }
  float a = ea_in[i];
  int p = 0;
#pragma unroll
  for (int k = 0; k < 64; ++k) p += (ts[k] < a) ? 1 : 0;
  int pos = atomicAdd(&cur[dst], 1);
  int2 v; v.x = src | (p << 20); v.y = __float_as_int(a);  // src < 2^20, p <= 64
  pay[pos] = v;
}

__global__ __launch_bounds__(256) void k_conv(
    const float* __restrict__ xin, const ushort16* __restrict__ xb,
    const int* __restrict__ offs, const int2* __restrict__ pay,
    const float2* __restrict__ ABg, const float* __restrict__ epsp,
    float* __restrict__ uout, int n) {
  __shared__ float2 ABs[65 * 64];  // 33280 B -> 4 blocks/CU
  {
    const float4* g4 = (const float4*)ABg;
    float4* s4 = (float4*)ABs;
    for (int i = threadIdx.x; i < 65 * 32; i += 256) s4[i] = g4[i];
  }
  __syncthreads();
  const int lane = threadIdx.x & 63;
  const int wid = threadIdx.x >> 6;
  const float scale = 1.0f + epsp[0];
  for (int node = blockIdx.x * 4 + wid; node < n; node += gridDim.x * 4) {
    int s = offs[node], e = offs[node + 1];
    float acc = 0.0f;
    int i = s;
    for (; i + 3 < e; i += 4) {  // 4 gathers in flight
      int2 q0 = pay[i], q1 = pay[i + 1], q2 = pay[i + 2], q3 = pay[i + 3];
      int s0 = q0.x & 0xFFFFF, p0 = (uint32)q0.x >> 20;
      int s1 = q1.x & 0xFFFFF, p1 = (uint32)q1.x >> 20;
      int s2 = q2.x & 0xFFFFF, p2 = (uint32)q2.x >> 20;
      int s3 = q3.x & 0xFFFFF, p3 = (uint32)q3.x >> 20;
      float x0 = bf2f(xb[(size_t)s0 * 64 + lane]);
      float x1 = bf2f(xb[(size_t)s1 * 64 + lane]);
      float x2 = bf2f(xb[(size_t)s2 * 64 + lane]);
      float x3 = bf2f(xb[(size_t)s3 * 64 + lane]);
      float2 ab0 = ABs[p0 * 64 + lane];
      float2 ab1 = ABs[p1 * 64 + lane];
      float2 ab2 = ABs[p2 * 64 + lane];
      float2 ab3 = ABs[p3 * 64 + lane];
      acc += fmaxf(fmaf(__int_as_float(q0.y), ab0.x, ab0.y) + x0, 0.0f);
      acc += fmaxf(fmaf(__int_as_float(q1.y), ab1.x, ab1.y) + x1, 0.0f);
      acc += fmaxf(fmaf(__int_as_float(q2.y), ab2.x, ab2.y) + x2, 0.0f);
      acc += fmaxf(fmaf(__int_as_float(q3.y), ab3.x, ab3.y) + x3, 0.0f);
    }
    for (; i < e; ++i) {
      int2 q0 = pay[i];
      int s0 = q0.x & 0xFFFFF, p0 = (uint32)q0.x >> 20;
      float x0 = bf2f(xb[(size_t)s0 * 64 + lane]);
      float2 ab0 = ABs[p0 * 64 + lane];
      acc += fmaxf(fmaf(__int_as_float(q0.y), ab0.x, ab0.y) + x0, 0.0f);
    }
    uout[(size_t)node * 64 + lane] = fmaf(scale, xin[(size_t)node * 64 + lane], acc);
  }
}

// thread-per-node MLP; u rows in LDS (stride 65 -> conflict-free), 64 reg accumulators,
// weights read wave-uniform (L1-hot broadcasts). Writes relu(mlp(u)) as f32 AND bf16.
__global__ __launch_bounds__(128) void k_mlp(
    const float* __restrict__ uin, float* __restrict__ hout, ushort16* __restrict__ houtb,
    const float* __restrict__ W1, const float* __restrict__ B1,
    const float* __restrict__ W2, const float* __restrict__ B2, int n) {
  __shared__ float row[128 * 65];
  const int tid = threadIdx.x;
  const size_t base = (size_t)blockIdx.x * 128 * 64;
  for (int k = 0; k < 64; ++k) {
    int f = k * 128 + tid;
    row[(f >> 6) * 65 + (f & 63)] = uin[base + f];
  }
  __syncthreads();
  float* r = &row[tid * 65];
  float h1[64];
#pragma unroll
  for (int i = 0; i < 64; ++i) h1[i] = B1[i];
  for (int j = 0; j < 64; ++j) {
    float uj = r[j];
    const float* wr = &W1[j * 64];
#pragma unroll
    for (int i = 0; i < 64; ++i) h1[i] = fmaf(uj, wr[i], h1[i]);
  }
#pragma unroll
  for (int i = 0; i < 64; ++i) r[i] = fmaxf(h1[i], 0.0f);  // own row: no sync needed
  float h2[64];
#pragma unroll
  for (int i = 0; i < 64; ++i) h2[i] = B2[i];
  for (int j = 0; j < 64; ++j) {
    float uj = r[j];
    const float* wr = &W2[j * 64];
#pragma unroll
    for (int i = 0; i < 64; ++i) h2[i] = fmaf(uj, wr[i], h2[i]);
  }
#pragma unroll
  for (int i = 0; i < 64; ++i) r[i] = fmaxf(h2[i], 0.0f);
  __syncthreads();
  for (int k = 0; k < 64; ++k) {
    int f = k * 128 + tid;
    hout[base + f] = row[(f >> 6) * 65 + (f & 63)];
  }
  // bf16 copy, coalesced 4B stores (2 features/thread/iter; pairs never straddle rows)
  uint32* ob = (uint32*)houtb;
  for (int k = 0; k < 32; ++k) {
    int f = k * 256 + tid * 2;
    uint32 lo = f2bf(row[(f >> 6) * 65 + (f & 63)]);
    uint32 hi = f2bf(row[(f >> 6) * 65 + ((f & 63) + 1)]);
    ob[(base + f) >> 1] = lo | (hi << 16);
  }
}

__global__ __launch_bounds__(128) void k_classify(
    const float* __restrict__ hin, const float* __restrict__ LW,
    const float* __restrict__ LB, float* __restrict__ out, int n) {
  __shared__ float row[128 * 65];
  const int tid = threadIdx.x;
  const size_t base = (size_t)blockIdx.x * 128 * 64;
  for (int k = 0; k < 64; ++k) {
    int f = k * 128 + tid;
    row[(f >> 6) * 65 + (f & 63)] = hin[base + f];
  }
  __syncthreads();
  int node = blockIdx.x * 128 + tid;
  float lg[40];
#pragma unroll
  for (int c = 0; c < 40; ++c) lg[c] = LB[c];
  const float* r = &row[tid * 65];
  for (int j = 0; j < 64; ++j) {
    float hj = r[j];
    const float* w = &LW[j * 40];
#pragma unroll
    for (int c = 0; c < 40; ++c) lg[c] = fmaf(hj, w[c], lg[c]);
  }
  if (node < n) {
    float mx = lg[0];
#pragma unroll
    for (int c = 1; c < 40; ++c) mx = fmaxf(mx, lg[c]);
    float se = 0.0f;
#pragma unroll
    for (int c = 0; c < 40; ++c) se += __expf(lg[c] - mx);
    float lse = mx + __logf(se);
    float* o = out + (size_t)node * 40;
#pragma unroll
    for (int q = 0; q < 10; ++q) {
      float4 v = make_float4(lg[q * 4] - lse, lg[q * 4 + 1] - lse,
                             lg[q * 4 + 2] - lse, lg[q * 4 + 3] - lse);
      *(float4*)(o + q * 4) = v;
    }
  }
}

extern "C" void kernel_launch(void* const* d_in, const int* in_sizes, int n_in,
                              void* d_out, int out_size, void* d_ws, size_t ws_size,
                              hipStream_t stream) {
  (void)n_in; (void)out_size; (void)ws_size;
  const float* x         = (const float*)d_in[0];
  const uint32* ei       = (const uint32*)d_in[1];
  const float* eattr     = (const float*)d_in[2];
  const float* e_w1 = (const float*)d_in[3];
  const float* e_b1 = (const float*)d_in[4];
  const float* e_w2 = (const float*)d_in[5];
  const float* e_b2 = (const float*)d_in[6];
  const float* eps1 = (const float*)d_in[7];
  const float* m1w1 = (const float*)d_in[8];
  const float* m1b1 = (const float*)d_in[9];
  const float* m1w2 = (const float*)d_in[10];
  const float* m1b2 = (const float*)d_in[11];
  const float* eps2 = (const float*)d_in[12];
  const float* m2w1 = (const float*)d_in[13];
  const float* m2b1 = (const float*)d_in[14];
  const float* m2w2 = (const float*)d_in[15];
  const float* m2b2 = (const float*)d_in[16];
  const float* linw = (const float*)d_in[17];
  const float* linb = (const float*)d_in[18];

  const int N = in_sizes[0] / 64;
  const int E = in_sizes[1] / 2;

  char* ws = (char*)d_ws;
  size_t off = 0;
  auto alloc = [&](size_t bytes, size_t align) {
    off = (off + align - 1) & ~(align - 1);
    size_t r = off; off += bytes; return r;
  };
  size_t oFlag = alloc(64, 64);
  size_t oT    = alloc(64 * 4, 64);
  size_t oAB   = alloc(65 * 64 * 8, 64);
  size_t oDeg  = alloc((size_t)N * 4, 128);
  size_t oOffs = alloc(((size_t)N + 1) * 4, 128);
  size_t oCur  = alloc((size_t)N * 4, 128);
  size_t oBsum = alloc(512 * 4, 128);
  size_t oPay  = alloc((size_t)E * 8, 256);
  size_t oXb   = alloc((size_t)N * 64 * 2 + 32768, 256);  // bf16 gather table (+tail pad)
  size_t oU    = alloc((size_t)N * 64 * 4 + 65536, 1024); // +pad: tail blocks read past N
  size_t oH    = alloc((size_t)N * 64 * 4 + 65536, 1024);

  int*    flag = (int*)(ws + oFlag);
  float*  t    = (float*)(ws + oT);
  float2* AB   = (float2*)(ws + oAB);
  int*    deg  = (int*)(ws + oDeg);
  int*    offs = (int*)(ws + oOffs);
  int*    cur  = (int*)(ws + oCur);
  int*    bsum = (int*)(ws + oBsum);
  int2*   pay  = (int2*)(ws + oPay);
  ushort16* xb = (ushort16*)(ws + oXb);
  float*  ubuf = (float*)(ws + oU);
  float*  hbuf = (float*)(ws + oH);

  hipMemsetAsync(ws + oFlag, 0, 64, stream);
  hipMemsetAsync(ws + oDeg, 0, (size_t)N * 4, stream);

  const int EB = (E + 255) / 256;
  const int NB = (N + 255) / 256;
  const int MB = (N + 127) / 128;
  const int CB = (N * 64 / 4 + 255) / 256;

  k_detect<<<1, 256, 0, stream>>>(ei, flag, E);
  k_setup<<<65, 256, 0, stream>>>(e_w1, e_b1, e_w2, e_b2, t, AB);
  k_cast<<<CB, 256, 0, stream>>>(x, xb, N * 64 / 4);
  k_hist<<<EB, 256, 0, stream>>>(ei, flag, deg, E);
  k_scan1<<<NB, 256, 0, stream>>>(deg, offs, bsum, N);
  k_scan2<<<1, 512, 0, stream>>>(bsum, NB);
  k_scan3<<<NB, 256, 0, stream>>>(offs, cur, bsum, N, E);
  k_scatter<<<EB, 256, 0, stream>>>(ei, eattr, flag, t, cur, pay, E);
  k_conv<<<2048, 256, 0, stream>>>(x, xb, offs, pay, AB, eps1, ubuf, N);
  k_mlp<<<MB, 128, 0, stream>>>(ubuf, hbuf, xb, m1w1, m1b1, m1w2, m1b2, N);
  k_conv<<<2048, 256, 0, stream>>>(hbuf, xb, offs, pay, AB, eps2, ubuf, N);
  k_mlp<<<MB, 128, 0, stream>>>(ubuf, hbuf, xb, m2w1, m2b1, m2w2, m2b2, N);
  k_classify<<<MB, 128, 0, stream>>>(hbuf, linw, linb, (float*)d_out, N);
}

// Round 5
// 499.352 us; speedup vs baseline: 2.4109x; 1.3390x over previous
//
#include <hip/hip_runtime.h>
#include <hip/hip_bf16.h>
#include <stdint.h>

// GINE net, MI355X. Pipeline:
//   k_detect : int32-vs-int64 width detection, SAMPLED (1 block, <=4 atomics)
//   k_setup  : piecewise-linear edge-MLP coeffs ABp[65][64] (packed bf16 A|B<<16) +
//              SORTED thresholds tsS[64] (+inf padded) for binary search.
//   k_cast   : f32 -> bf16 copy of node features (halves gather line traffic in k_conv)
//   CSR build, radix style:
//     k_bcount: histogram of dst>>7 (1024 buckets) via LDS, flushed once per block
//     k_bscan : exclusive scan of 1024 buckets -> bucketOffs/bucketCur; offs[N]=E
//     k_bpart : partition edges into buckets; LDS ranks, ONE global atomic per
//               (block,bucket); writes (srcp, a, dstLocal) into bucket segments
//     k_blocal: per-bucket (128 dst nodes) LDS histogram + scan -> final offs[]/pay[]
//   k_conv   : u = (1+eps)*x + sum relu(bf16(x[src]) + a*A_p + B_p); AB packed bf16
//              in LDS (16.6KB -> 8 blocks/CU)
//   k_mlp    : node MLP, thread-per-node, LDS rows (stride 65); writes f32 + bf16
//   k_classify: logits + log_softmax
// R4 FAILURE ROOT CAUSE (fixed): 6-step branchless lower_bound saturates at p=63
// (sum of steps = 63), so a > all 64 thresholds selected piece 63, not 64. Fixed
// with a final correction step (p += tss[p] < a), verified exhaustively at n=4/8.

typedef unsigned int uint32;
typedef unsigned short ushort16;
typedef unsigned char u8;

static __device__ __forceinline__ unsigned short f2bf(float f) {
  __hip_bfloat16 h = __float2bfloat16(f);
  return *reinterpret_cast<unsigned short*>(&h);
}
static __device__ __forceinline__ float bf2f(unsigned short u) {
  return __uint_as_float(((uint32)u) << 16);
}

// Sampled width detection: odd 32-bit words among the first 2E words are src values
// (int32 layout, ~all nonzero) or int64 high-halves (all zero since idx < 2^20).
__global__ void k_detect(const uint32* __restrict__ w, int* __restrict__ flag, int E) {
  int cnt = (E < 4096) ? E : 4096;
  int nz = 0;
  for (int i = threadIdx.x; i < cnt; i += 256) nz |= (w[2 * (size_t)i + 1] != 0u);
  if (__any(nz) && (threadIdx.x & 63) == 0) atomicOr(flag, 1);
}

// One block per piece p (65 blocks). w2/b2 staged in LDS. Block 0 additionally emits
// sorted thresholds tsS (ascending; invalid units -> +inf at the tail).
__global__ __launch_bounds__(256) void k_setup(
    const float* __restrict__ w1, const float* __restrict__ b1,
    const float* __restrict__ w2, const float* __restrict__ b2,
    float* __restrict__ tsS, uint32* __restrict__ ABp) {
  __shared__ float w2s[64 * 64];   // 16 KB
  __shared__ float b2s[64];
  __shared__ float w1s[64], b1s[64], ts[64];
  __shared__ int rs[64], ms[64], vs[64];
  const int tid = threadIdx.x;
  const int p = blockIdx.x;

  {
    const float4* g4 = (const float4*)w2;
    float4* s4 = (float4*)w2s;
    for (int i = tid; i < 64 * 16; i += 256) s4[i] = g4[i];
    if (tid < 64) b2s[tid] = b2[tid];
  }
  if (tid < 64) {
    float w = w1[tid], b = b1[tid];
    w1s[tid] = w; b1s[tid] = b;
    int v = (w != 0.0f);
    vs[tid] = v;
    ts[tid] = v ? (-b / w) : 0.0f;
  }
  __syncthreads();
  if (tid < 64) {
    float tk = ts[tid];
    int r = 0, m = 0;
    for (int k = 0; k < 64; ++k) if (vs[k]) { r += (ts[k] < tk) ? 1 : 0; m += (ts[k] == tk) ? 1 : 0; }
    rs[tid] = r; ms[tid] = m;
    if (p == 0) {
      // stable sorted position: valid keys first (ties by index), invalid -> +inf tail
      int pos;
      if (vs[tid]) {
        int c = 0;
        for (int j = 0; j < 64; ++j)
          if (vs[j] && (ts[j] < tk || (ts[j] == tk && j < tid))) c++;
        pos = c;
      } else {
        int c = 0;
        for (int j = 0; j < 64; ++j) if (vs[j]) c++;
        for (int j = 0; j < tid; ++j) if (!vs[j]) c++;
        pos = c;
      }
      tsS[pos] = vs[tid] ? tk : __builtin_inff();
    }
  }
  __syncthreads();
  // piece p = #{thresholds < a}. Unit k active at piece p:
  //   w1>0: p >= r_k+m_k ; w1<0: p <= r_k ; w1==0: b1>0
  if (tid < 64) {
    const int j = tid;
    float accA = 0.0f, accB = b2s[j];
    for (int k = 0; k < 64; ++k) {
      bool act;
      if (vs[k]) act = (w1s[k] > 0.0f) ? (p >= rs[k] + ms[k]) : (p <= rs[k]);
      else       act = (b1s[k] > 0.0f);
      if (act) { float wv = w2s[k * 64 + j]; accA = fmaf(w1s[k], wv, accA); accB = fmaf(b1s[k], wv, accB); }
    }
    ABp[p * 64 + j] = (uint32)f2bf(accA) | ((uint32)f2bf(accB) << 16);
  }
}

__global__ void k_cast(const float* __restrict__ in, ushort16* __restrict__ out, int n4) {
  int i = blockIdx.x * blockDim.x + threadIdx.x;
  if (i >= n4) return;
  float4 v = ((const float4*)in)[i];
  ushort4 o;
  o.x = f2bf(v.x); o.y = f2bf(v.y); o.z = f2bf(v.z); o.w = f2bf(v.w);
  ((ushort4*)out)[i] = o;
}

// ---- CSR build: radix partition by dst>>7 ----

__global__ __launch_bounds__(256) void k_bcount(
    const uint32* __restrict__ ei, const int* __restrict__ flag,
    int* __restrict__ hist1, int E) {
  __shared__ int h[1024];
  for (int i = threadIdx.x; i < 1024; i += 256) h[i] = 0;
  __syncthreads();
  bool is64 = (*flag == 0);
  for (int i = blockIdx.x * blockDim.x + threadIdx.x; i < E; i += gridDim.x * blockDim.x) {
    int dst = is64 ? (int)ei[2 * ((size_t)E + i)] : (int)ei[(size_t)E + i];
    atomicAdd(&h[dst >> 7], 1);
  }
  __syncthreads();
  for (int i = threadIdx.x; i < 1024; i += 256)
    if (h[i]) atomicAdd(&hist1[i], h[i]);
}

__global__ __launch_bounds__(256) void k_bscan(
    const int* __restrict__ hist1, int* __restrict__ bOffs, int* __restrict__ bCur,
    int* __restrict__ offs, int N, int E) {
  __shared__ int psum[256];
  const int tid = threadIdx.x;
  int v0 = hist1[tid * 4 + 0], v1 = hist1[tid * 4 + 1];
  int v2 = hist1[tid * 4 + 2], v3 = hist1[tid * 4 + 3];
  int sum = v0 + v1 + v2 + v3;
  psum[tid] = sum;
  __syncthreads();
  for (int d = 1; d < 256; d <<= 1) {
    int add = (tid >= d) ? psum[tid - d] : 0;
    __syncthreads();
    psum[tid] += add;
    __syncthreads();
  }
  int run = psum[tid] - sum;  // exclusive
  bOffs[tid * 4 + 0] = run; bCur[tid * 4 + 0] = run; run += v0;
  bOffs[tid * 4 + 1] = run; bCur[tid * 4 + 1] = run; run += v1;
  bOffs[tid * 4 + 2] = run; bCur[tid * 4 + 2] = run; run += v2;
  bOffs[tid * 4 + 3] = run; bCur[tid * 4 + 3] = run; run += v3;
  if (tid == 255) bOffs[1024] = run;  // == E
  if (tid == 0) offs[N] = E;
}

// tile = 2048 edges/block, 8 per thread. Ranks via LDS atomics; one global atomic
// per (block, nonempty bucket); writes land in per-block contiguous bucket segments.
__global__ __launch_bounds__(256) void k_bpart(
    const uint32* __restrict__ ei, const float* __restrict__ ea,
    const int* __restrict__ flag, const float* __restrict__ tsSg,
    int* __restrict__ bCur, int* __restrict__ srcp_arr,
    float* __restrict__ a_arr, u8* __restrict__ dstl_arr, int E) {
  __shared__ int cnt[1024];
  __shared__ float tss[64];
  const int tid = threadIdx.x;
  for (int i = tid; i < 1024; i += 256) cnt[i] = 0;
  if (tid < 64) tss[tid] = tsSg[tid];
  __syncthreads();
  bool is64 = (*flag == 0);
  const int base0 = blockIdx.x * 2048;
  int dstv[8], srcv[8], rk[8];
  float av[8];
#pragma unroll
  for (int e = 0; e < 8; ++e) {
    int idx = base0 + e * 256 + tid;
    if (idx < E) {
      int src, dst;
      if (is64) { src = (int)ei[2 * (size_t)idx]; dst = (int)ei[2 * ((size_t)E + idx)]; }
      else      { src = (int)ei[(size_t)idx];     dst = (int)ei[(size_t)E + idx]; }
      dstv[e] = dst; srcv[e] = src; av[e] = ea[idx];
      rk[e] = atomicAdd(&cnt[dst >> 7], 1);
    } else dstv[e] = -1;
  }
  __syncthreads();
  for (int b = tid; b < 1024; b += 256) {
    int c = cnt[b];
    cnt[b] = c ? atomicAdd(&bCur[b], c) : 0;  // cnt[b] becomes this block's base
  }
  __syncthreads();
#pragma unroll
  for (int e = 0; e < 8; ++e) {
    if (dstv[e] < 0) continue;
    float a = av[e];
    // p = #{sorted thresholds < a}. 6-step uniform search saturates at 63
    // (sum of steps = 63); final correction step admits p = 64. (R4 bug.)
    int p = 0;
#pragma unroll
    for (int s = 32; s > 0; s >>= 1) if (tss[p + s - 1] < a) p += s;
    if (tss[p] < a) ++p;   // p <= 63 here, so index is safe; afterwards p <= 64
    int pos = cnt[dstv[e] >> 7] + rk[e];
    srcp_arr[pos] = srcv[e] | (p << 20);
    a_arr[pos] = a;
    dstl_arr[pos] = (u8)(dstv[e] & 127);
  }
}

// One block per bucket (128 dst nodes): LDS histogram + scan -> final offs and
// dst-ordered pay[]. All global writes confined to the bucket's contiguous region.
__global__ __launch_bounds__(256) void k_blocal(
    const int* __restrict__ bOffs, const int* __restrict__ srcp_arr,
    const float* __restrict__ a_arr, const u8* __restrict__ dstl_arr,
    int* __restrict__ offs, int2* __restrict__ pay, int N) {
  __shared__ int h[128], cur[128], ps[128];
  const int tid = threadIdx.x;
  const int b = blockIdx.x;
  const int s = bOffs[b], e2 = bOffs[b + 1];
  if (tid < 128) h[tid] = 0;
  __syncthreads();
  for (int j = s + tid; j < e2; j += 256) atomicAdd(&h[dstl_arr[j]], 1);
  __syncthreads();
  if (tid < 128) ps[tid] = h[tid];
  __syncthreads();
  for (int d = 1; d < 128; d <<= 1) {
    int add = (tid < 128 && tid >= d) ? ps[tid - d] : 0;
    __syncthreads();
    if (tid < 128) ps[tid] += add;
    __syncthreads();
  }
  if (tid < 128) {
    int ex = s + ps[tid] - h[tid];  // exclusive, absolute
    cur[tid] = ex;
    int nd = b * 128 + tid;
    if (nd < N) offs[nd] = ex;
  }
  __syncthreads();
  for (int j = s + tid; j < e2; j += 256) {
    int pos = atomicAdd(&cur[dstl_arr[j]], 1);
    pay[pos] = make_int2(srcp_arr[j], __float_as_int(a_arr[j]));
  }
}

// ---- conv / mlp / classify ----

__global__ __launch_bounds__(256) void k_conv(
    const float* __restrict__ xin, const ushort16* __restrict__ xb,
    const int* __restrict__ offs, const int2* __restrict__ pay,
    const uint32* __restrict__ ABp, const float* __restrict__ epsp,
    float* __restrict__ uout, int n) {
  __shared__ uint32 ABs[65 * 64];  // packed bf16 A|B<<16: 16.6 KB -> 8 blocks/CU
  {
    const uint4* g4 = (const uint4*)ABp;
    uint4* s4 = (uint4*)ABs;
    for (int i = threadIdx.x; i < 65 * 16; i += 256) s4[i] = g4[i];
  }
  __syncthreads();
  const int lane = threadIdx.x & 63;
  const int wid = threadIdx.x >> 6;
  const float scale = 1.0f + epsp[0];
  for (int node = blockIdx.x * 4 + wid; node < n; node += gridDim.x * 4) {
    int s = offs[node], e = offs[node + 1];
    float acc = 0.0f;
    int i = s;
    for (; i + 3 < e; i += 4) {  // 4 gathers in flight
      int2 q0 = pay[i], q1 = pay[i + 1], q2 = pay[i + 2], q3 = pay[i + 3];
      int s0 = q0.x & 0xFFFFF, p0 = (uint32)q0.x >> 20;
      int s1 = q1.x & 0xFFFFF, p1 = (uint32)q1.x >> 20;
      int s2 = q2.x & 0xFFFFF, p2 = (uint32)q2.x >> 20;
      int s3 = q3.x & 0xFFFFF, p3 = (uint32)q3.x >> 20;
      float x0 = bf2f(xb[(size_t)s0 * 64 + lane]);
      float x1 = bf2f(xb[(size_t)s1 * 64 + lane]);
      float x2 = bf2f(xb[(size_t)s2 * 64 + lane]);
      float x3 = bf2f(xb[(size_t)s3 * 64 + lane]);
      uint32 u0 = ABs[p0 * 64 + lane], u1 = ABs[p1 * 64 + lane];
      uint32 u2 = ABs[p2 * 64 + lane], u3 = ABs[p3 * 64 + lane];
      acc += fmaxf(fmaf(__int_as_float(q0.y), __uint_as_float(u0 << 16), __uint_as_float(u0 & 0xffff0000u)) + x0, 0.0f);
      acc += fmaxf(fmaf(__int_as_float(q1.y), __uint_as_float(u1 << 16), __uint_as_float(u1 & 0xffff0000u)) + x1, 0.0f);
      acc += fmaxf(fmaf(__int_as_float(q2.y), __uint_as_float(u2 << 16), __uint_as_float(u2 & 0xffff0000u)) + x2, 0.0f);
      acc += fmaxf(fmaf(__int_as_float(q3.y), __uint_as_float(u3 << 16), __uint_as_float(u3 & 0xffff0000u)) + x3, 0.0f);
    }
    for (; i < e; ++i) {
      int2 q0 = pay[i];
      int s0 = q0.x & 0xFFFFF, p0 = (uint32)q0.x >> 20;
      float x0 = bf2f(xb[(size_t)s0 * 64 + lane]);
      uint32 u0 = ABs[p0 * 64 + lane];
      acc += fmaxf(fmaf(__int_as_float(q0.y), __uint_as_float(u0 << 16), __uint_as_float(u0 & 0xffff0000u)) + x0, 0.0f);
    }
    uout[(size_t)node * 64 + lane] = fmaf(scale, xin[(size_t)node * 64 + lane], acc);
  }
}

// thread-per-node MLP; u rows in LDS (stride 65 -> conflict-free), 64 reg accumulators,
// weights read wave-uniform (L1-hot broadcasts). Writes relu(mlp(u)) as f32 AND bf16.
__global__ __launch_bounds__(128) void k_mlp(
    const float* __restrict__ uin, float* __restrict__ hout, ushort16* __restrict__ houtb,
    const float* __restrict__ W1, const float* __restrict__ B1,
    const float* __restrict__ W2, const float* __restrict__ B2, int n) {
  __shared__ float row[128 * 65];
  const int tid = threadIdx.x;
  const size_t base = (size_t)blockIdx.x * 128 * 64;
  for (int k = 0; k < 64; ++k) {
    int f = k * 128 + tid;
    row[(f >> 6) * 65 + (f & 63)] = uin[base + f];
  }
  __syncthreads();
  float* r = &row[tid * 65];
  float h1[64];
#pragma unroll
  for (int i = 0; i < 64; ++i) h1[i] = B1[i];
  for (int j = 0; j < 64; ++j) {
    float uj = r[j];
    const float* wr = &W1[j * 64];
#pragma unroll
    for (int i = 0; i < 64; ++i) h1[i] = fmaf(uj, wr[i], h1[i]);
  }
#pragma unroll
  for (int i = 0; i < 64; ++i) r[i] = fmaxf(h1[i], 0.0f);  // own row: no sync needed
  float h2[64];
#pragma unroll
  for (int i = 0; i < 64; ++i) h2[i] = B2[i];
  for (int j = 0; j < 64; ++j) {
    float uj = r[j];
    const float* wr = &W2[j * 64];
#pragma unroll
    for (int i = 0; i < 64; ++i) h2[i] = fmaf(uj, wr[i], h2[i]);
  }
#pragma unroll
  for (int i = 0; i < 64; ++i) r[i] = fmaxf(h2[i], 0.0f);
  __syncthreads();
  for (int k = 0; k < 64; ++k) {
    int f = k * 128 + tid;
    hout[base + f] = row[(f >> 6) * 65 + (f & 63)];
  }
  uint32* ob = (uint32*)houtb;
  for (int k = 0; k < 32; ++k) {
    int f = k * 256 + tid * 2;
    uint32 lo = f2bf(row[(f >> 6) * 65 + (f & 63)]);
    uint32 hi = f2bf(row[(f >> 6) * 65 + ((f & 63) + 1)]);
    ob[(base + f) >> 1] = lo | (hi << 16);
  }
}

__global__ __launch_bounds__(128) void k_classify(
    const float* __restrict__ hin, const float* __restrict__ LW,
    const float* __restrict__ LB, float* __restrict__ out, int n) {
  __shared__ float row[128 * 65];
  const int tid = threadIdx.x;
  const size_t base = (size_t)blockIdx.x * 128 * 64;
  for (int k = 0; k < 64; ++k) {
    int f = k * 128 + tid;
    row[(f >> 6) * 65 + (f & 63)] = hin[base + f];
  }
  __syncthreads();
  int node = blockIdx.x * 128 + tid;
  float lg[40];
#pragma unroll
  for (int c = 0; c < 40; ++c) lg[c] = LB[c];
  const float* r = &row[tid * 65];
  for (int j = 0; j < 64; ++j) {
    float hj = r[j];
    const float* w = &LW[j * 40];
#pragma unroll
    for (int c = 0; c < 40; ++c) lg[c] = fmaf(hj, w[c], lg[c]);
  }
  if (node < n) {
    float mx = lg[0];
#pragma unroll
    for (int c = 1; c < 40; ++c) mx = fmaxf(mx, lg[c]);
    float se = 0.0f;
#pragma unroll
    for (int c = 0; c < 40; ++c) se += __expf(lg[c] - mx);
    float lse = mx + __logf(se);
    float* o = out + (size_t)node * 40;
#pragma unroll
    for (int q = 0; q < 10; ++q) {
      float4 v = make_float4(lg[q * 4] - lse, lg[q * 4 + 1] - lse,
                             lg[q * 4 + 2] - lse, lg[q * 4 + 3] - lse);
      *(float4*)(o + q * 4) = v;
    }
  }
}

extern "C" void kernel_launch(void* const* d_in, const int* in_sizes, int n_in,
                              void* d_out, int out_size, void* d_ws, size_t ws_size,
                              hipStream_t stream) {
  (void)n_in; (void)out_size; (void)ws_size;
  const float* x     = (const float*)d_in[0];
  const uint32* ei   = (const uint32*)d_in[1];
  const float* eattr = (const float*)d_in[2];
  const float* e_w1 = (const float*)d_in[3];
  const float* e_b1 = (const float*)d_in[4];
  const float* e_w2 = (const float*)d_in[5];
  const float* e_b2 = (const float*)d_in[6];
  const float* eps1 = (const float*)d_in[7];
  const float* m1w1 = (const float*)d_in[8];
  const float* m1b1 = (const float*)d_in[9];
  const float* m1w2 = (const float*)d_in[10];
  const float* m1b2 = (const float*)d_in[11];
  const float* eps2 = (const float*)d_in[12];
  const float* m2w1 = (const float*)d_in[13];
  const float* m2b1 = (const float*)d_in[14];
  const float* m2w2 = (const float*)d_in[15];
  const float* m2b2 = (const float*)d_in[16];
  const float* linw = (const float*)d_in[17];
  const float* linb = (const float*)d_in[18];

  const int N = in_sizes[0] / 64;
  const int E = in_sizes[1] / 2;
  const int NB128 = (N + 127) / 128;   // buckets used (<= 1024 for N <= 131072)

  char* ws = (char*)d_ws;
  size_t off = 0;
  auto alloc = [&](size_t bytes, size_t align) {
    off = (off + align - 1) & ~(align - 1);
    size_t r = off; off += bytes; return r;
  };
  size_t oFlag = alloc(64, 64);
  size_t oT    = alloc(64 * 4, 64);
  size_t oAB   = alloc(65 * 64 * 4, 64);
  size_t oH1   = alloc(1024 * 4, 128);
  size_t oBO   = alloc(1025 * 4, 128);
  size_t oBC   = alloc(1024 * 4, 128);
  size_t oOffs = alloc(((size_t)N + 1) * 4, 128);
  size_t oPay  = alloc((size_t)E * 8, 256);
  size_t oXb   = alloc((size_t)N * 64 * 2 + 32768, 256);
  size_t oU    = alloc((size_t)N * 64 * 4 + 65536, 1024); // +pad: tail blocks read past N
  size_t oH    = alloc((size_t)N * 64 * 4 + 65536, 1024);

  int*    flag = (int*)(ws + oFlag);
  float*  tsS  = (float*)(ws + oT);
  uint32* ABp  = (uint32*)(ws + oAB);
  int*    h1   = (int*)(ws + oH1);
  int*    bOffs= (int*)(ws + oBO);
  int*    bCur = (int*)(ws + oBC);
  int*    offs = (int*)(ws + oOffs);
  int2*   pay  = (int2*)(ws + oPay);
  ushort16* xb = (ushort16*)(ws + oXb);
  float*  ubuf = (float*)(ws + oU);
  float*  hbuf = (float*)(ws + oH);
  // partition scratch aliases ubuf (14.4 MB <= 25.6 MB); consumed before conv1 writes it
  int*   srcp_arr = (int*)(ws + oU);
  float* a_arr    = (float*)(ws + oU + (size_t)E * 4);
  u8*    dstl_arr = (u8*)(ws + oU + (size_t)E * 8);

  hipMemsetAsync(ws + oFlag, 0, 64, stream);
  hipMemsetAsync(ws + oH1, 0, 1024 * 4, stream);

  const int MB = (N + 127) / 128;
  const int CB = (N * 64 / 4 + 255) / 256;
  const int PB = (E + 2047) / 2048;

  k_detect<<<1, 256, 0, stream>>>(ei, flag, E);
  k_setup<<<65, 256, 0, stream>>>(e_w1, e_b1, e_w2, e_b2, tsS, ABp);
  k_cast<<<CB, 256, 0, stream>>>(x, xb, N * 64 / 4);
  k_bcount<<<1024, 256, 0, stream>>>(ei, flag, h1, E);
  k_bscan<<<1, 256, 0, stream>>>(h1, bOffs, bCur, offs, N, E);
  k_bpart<<<PB, 256, 0, stream>>>(ei, eattr, flag, tsS, bCur, srcp_arr, a_arr, dstl_arr, E);
  k_blocal<<<NB128, 256, 0, stream>>>(bOffs, srcp_arr, a_arr, dstl_arr, offs, pay, N);
  k_conv<<<2048, 256, 0, stream>>>(x, xb, offs, pay, ABp, eps1, ubuf, N);
  k_mlp<<<MB, 128, 0, stream>>>(ubuf, hbuf, xb, m1w1, m1b1, m1w2, m1b2, N);
  k_conv<<<2048, 256, 0, stream>>>(hbuf, xb, offs, pay, ABp, eps2, ubuf, N);
  k_mlp<<<MB, 128, 0, stream>>>(ubuf, hbuf, xb, m2w1, m2b1, m2w2, m2b2, N);
  k_classify<<<MB, 128, 0, stream>>>(hbuf, linw, linb, (float*)d_out, N);
}

// Round 6
// 497.310 us; speedup vs baseline: 2.4208x; 1.0041x over previous
//
#include <hip/hip_runtime.h>
#include <hip/hip_bf16.h>
#include <stdint.h>

// GINE net, MI355X. Pipeline (R6):
//   k_setup  : piecewise-linear edge-MLP coeffs ABp[65][64] (packed bf16 A|B<<16) +
//              SORTED thresholds tsS[64] (+inf padded) for binary search
//   k_cast   : f32 -> bf16 node-feature gather table
//   CSR build (radix by dst>>7): k_bcount -> k_bscan -> k_bpart -> k_blocal.
//              int32/int64 width detection inlined per-block (64-sample, P(err)~1e-320)
//   k_conv   : u = bf16((1+eps)*x + sum relu(bf16(x[src]) + a*A_p + B_p));
//              8-wide gather pipeline (R5 was 4-wide, VALUBusy 53% latency-bound),
//              uint32 gather indices (saddr+voffset form), bf16-only u output
//   k_mlp    : node MLP; bf16 LDS rows stride 66 (16.9KB, was 33KB f32 -> 2x occupancy)
//   k_classify: logits + log_softmax

typedef unsigned int uint32;
typedef unsigned short ushort16;
typedef unsigned char u8;

static __device__ __forceinline__ unsigned short f2bf(float f) {
  __hip_bfloat16 h = __float2bfloat16(f);
  return *reinterpret_cast<unsigned short*>(&h);
}
static __device__ __forceinline__ float bf2f(unsigned short u) {
  return __uint_as_float(((uint32)u) << 16);
}

// One block per piece p (65 blocks). w2/b2 staged in LDS. Block 0 additionally emits
// sorted thresholds tsS (ascending; invalid units -> +inf at the tail).
__global__ __launch_bounds__(256) void k_setup(
    const float* __restrict__ w1, const float* __restrict__ b1,
    const float* __restrict__ w2, const float* __restrict__ b2,
    float* __restrict__ tsS, uint32* __restrict__ ABp) {
  __shared__ float w2s[64 * 64];   // 16 KB
  __shared__ float b2s[64];
  __shared__ float w1s[64], b1s[64], ts[64];
  __shared__ int rs[64], ms[64], vs[64];
  const int tid = threadIdx.x;
  const int p = blockIdx.x;

  {
    const float4* g4 = (const float4*)w2;
    float4* s4 = (float4*)w2s;
    for (int i = tid; i < 64 * 16; i += 256) s4[i] = g4[i];
    if (tid < 64) b2s[tid] = b2[tid];
  }
  if (tid < 64) {
    float w = w1[tid], b = b1[tid];
    w1s[tid] = w; b1s[tid] = b;
    int v = (w != 0.0f);
    vs[tid] = v;
    ts[tid] = v ? (-b / w) : 0.0f;
  }
  __syncthreads();
  if (tid < 64) {
    float tk = ts[tid];
    int r = 0, m = 0;
    for (int k = 0; k < 64; ++k) if (vs[k]) { r += (ts[k] < tk) ? 1 : 0; m += (ts[k] == tk) ? 1 : 0; }
    rs[tid] = r; ms[tid] = m;
    if (p == 0) {
      int pos;
      if (vs[tid]) {
        int c = 0;
        for (int j = 0; j < 64; ++j)
          if (vs[j] && (ts[j] < tk || (ts[j] == tk && j < tid))) c++;
        pos = c;
      } else {
        int c = 0;
        for (int j = 0; j < 64; ++j) if (vs[j]) c++;
        for (int j = 0; j < tid; ++j) if (!vs[j]) c++;
        pos = c;
      }
      tsS[pos] = vs[tid] ? tk : __builtin_inff();
    }
  }
  __syncthreads();
  // piece p = #{thresholds < a}. Unit k active at piece p:
  //   w1>0: p >= r_k+m_k ; w1<0: p <= r_k ; w1==0: b1>0
  if (tid < 64) {
    const int j = tid;
    float accA = 0.0f, accB = b2s[j];
    for (int k = 0; k < 64; ++k) {
      bool act;
      if (vs[k]) act = (w1s[k] > 0.0f) ? (p >= rs[k] + ms[k]) : (p <= rs[k]);
      else       act = (b1s[k] > 0.0f);
      if (act) { float wv = w2s[k * 64 + j]; accA = fmaf(w1s[k], wv, accA); accB = fmaf(b1s[k], wv, accB); }
    }
    ABp[p * 64 + j] = (uint32)f2bf(accA) | ((uint32)f2bf(accB) << 16);
  }
}

__global__ void k_cast(const float* __restrict__ in, ushort16* __restrict__ out, int n4) {
  int i = blockIdx.x * blockDim.x + threadIdx.x;
  if (i >= n4) return;
  float4 v = ((const float4*)in)[i];
  ushort4 o;
  o.x = f2bf(v.x); o.y = f2bf(v.y); o.z = f2bf(v.z); o.w = f2bf(v.w);
  ((ushort4*)out)[i] = o;
}

// Inline width detection: odd 32-bit words of edge_index are int64 high-halves
// (all zero, idx < 2^20) or int32 src values (~never 64 consecutive zeros).
static __device__ __forceinline__ bool detect_is64(const uint32* ei, int E, int tid, int* sflag) {
  if (tid < 64) {
    int lim = (E < 64) ? E : 64;
    int nz = (tid < lim) ? (ei[2 * (size_t)tid + 1] != 0u) : 0;
    nz = __any(nz);
    if (tid == 0) *sflag = !nz;
  }
  __syncthreads();
  return *sflag != 0;
}

// ---- CSR build: radix partition by dst>>7 ----

__global__ __launch_bounds__(256) void k_bcount(
    const uint32* __restrict__ ei, int* __restrict__ hist1, int E) {
  __shared__ int h[1024];
  __shared__ int sIs64;
  for (int i = threadIdx.x; i < 1024; i += 256) h[i] = 0;
  bool is64 = detect_is64(ei, E, threadIdx.x, &sIs64);  // has __syncthreads
  for (int i = blockIdx.x * blockDim.x + threadIdx.x; i < E; i += gridDim.x * blockDim.x) {
    int dst = is64 ? (int)ei[2 * ((size_t)E + i)] : (int)ei[(size_t)E + i];
    atomicAdd(&h[dst >> 7], 1);
  }
  __syncthreads();
  for (int i = threadIdx.x; i < 1024; i += 256)
    if (h[i]) atomicAdd(&hist1[i], h[i]);
}

__global__ __launch_bounds__(256) void k_bscan(
    const int* __restrict__ hist1, int* __restrict__ bOffs, int* __restrict__ bCur,
    int* __restrict__ offs, int N, int E) {
  __shared__ int psum[256];
  const int tid = threadIdx.x;
  int v0 = hist1[tid * 4 + 0], v1 = hist1[tid * 4 + 1];
  int v2 = hist1[tid * 4 + 2], v3 = hist1[tid * 4 + 3];
  int sum = v0 + v1 + v2 + v3;
  psum[tid] = sum;
  __syncthreads();
  for (int d = 1; d < 256; d <<= 1) {
    int add = (tid >= d) ? psum[tid - d] : 0;
    __syncthreads();
    psum[tid] += add;
    __syncthreads();
  }
  int run = psum[tid] - sum;  // exclusive
  bOffs[tid * 4 + 0] = run; bCur[tid * 4 + 0] = run; run += v0;
  bOffs[tid * 4 + 1] = run; bCur[tid * 4 + 1] = run; run += v1;
  bOffs[tid * 4 + 2] = run; bCur[tid * 4 + 2] = run; run += v2;
  bOffs[tid * 4 + 3] = run; bCur[tid * 4 + 3] = run; run += v3;
  if (tid == 255) bOffs[1024] = run;  // == E
  if (tid == 0) offs[N] = E;
}

// tile = 2048 edges/block, 8 per thread. Ranks via LDS atomics; one global atomic
// per (block, nonempty bucket); writes land in per-block contiguous bucket segments.
__global__ __launch_bounds__(256) void k_bpart(
    const uint32* __restrict__ ei, const float* __restrict__ ea,
    const float* __restrict__ tsSg, int* __restrict__ bCur,
    int* __restrict__ srcp_arr, float* __restrict__ a_arr,
    u8* __restrict__ dstl_arr, int E) {
  __shared__ int cnt[1024];
  __shared__ float tss[64];
  __shared__ int sIs64;
  const int tid = threadIdx.x;
  for (int i = tid; i < 1024; i += 256) cnt[i] = 0;
  if (tid >= 64 && tid < 128) tss[tid - 64] = tsSg[tid - 64];
  bool is64 = detect_is64(ei, E, tid, &sIs64);  // has __syncthreads
  const int base0 = blockIdx.x * 2048;
  int dstv[8], srcv[8], rk[8];
  float av[8];
#pragma unroll
  for (int e = 0; e < 8; ++e) {
    int idx = base0 + e * 256 + tid;
    if (idx < E) {
      int src, dst;
      if (is64) { src = (int)ei[2 * (size_t)idx]; dst = (int)ei[2 * ((size_t)E + idx)]; }
      else      { src = (int)ei[(size_t)idx];     dst = (int)ei[(size_t)E + idx]; }
      dstv[e] = dst; srcv[e] = src; av[e] = ea[idx];
      rk[e] = atomicAdd(&cnt[dst >> 7], 1);
    } else dstv[e] = -1;
  }
  __syncthreads();
  for (int b = tid; b < 1024; b += 256) {
    int c = cnt[b];
    cnt[b] = c ? atomicAdd(&bCur[b], c) : 0;  // cnt[b] becomes this block's base
  }
  __syncthreads();
#pragma unroll
  for (int e = 0; e < 8; ++e) {
    if (dstv[e] < 0) continue;
    float a = av[e];
    // p = #{sorted thresholds < a}. 6-step search saturates at 63 (sum of steps
    // = 63); final correction step admits p = 64. (R4 bug, fixed R5.)
    int p = 0;
#pragma unroll
    for (int s = 32; s > 0; s >>= 1) if (tss[p + s - 1] < a) p += s;
    if (tss[p] < a) ++p;
    int pos = cnt[dstv[e] >> 7] + rk[e];
    srcp_arr[pos] = srcv[e] | (p << 20);
    a_arr[pos] = a;
    dstl_arr[pos] = (u8)(dstv[e] & 127);
  }
}

// One block per bucket (128 dst nodes): LDS histogram + scan -> final offs and
// dst-ordered pay[]. All global writes confined to the bucket's contiguous region.
__global__ __launch_bounds__(256) void k_blocal(
    const int* __restrict__ bOffs, const int* __restrict__ srcp_arr,
    const float* __restrict__ a_arr, const u8* __restrict__ dstl_arr,
    int* __restrict__ offs, int2* __restrict__ pay, int N) {
  __shared__ int h[128], cur[128], ps[128];
  const int tid = threadIdx.x;
  const int b = blockIdx.x;
  const int s = bOffs[b], e2 = bOffs[b + 1];
  if (tid < 128) h[tid] = 0;
  __syncthreads();
  for (int j = s + tid; j < e2; j += 256) atomicAdd(&h[dstl_arr[j]], 1);
  __syncthreads();
  if (tid < 128) ps[tid] = h[tid];
  __syncthreads();
  for (int d = 1; d < 128; d <<= 1) {
    int add = (tid < 128 && tid >= d) ? ps[tid - d] : 0;
    __syncthreads();
    if (tid < 128) ps[tid] += add;
    __syncthreads();
  }
  if (tid < 128) {
    int ex = s + ps[tid] - h[tid];  // exclusive, absolute
    cur[tid] = ex;
    int nd = b * 128 + tid;
    if (nd < N) offs[nd] = ex;
  }
  __syncthreads();
  for (int j = s + tid; j < e2; j += 256) {
    int pos = atomicAdd(&cur[dstl_arr[j]], 1);
    pay[pos] = make_int2(srcp_arr[j], __float_as_int(a_arr[j]));
  }
}

// ---- conv / mlp / classify ----

__global__ __launch_bounds__(256) void k_conv(
    const float* __restrict__ xin, const ushort16* __restrict__ xb,
    const int* __restrict__ offs, const int2* __restrict__ pay,
    const uint32* __restrict__ ABp, const float* __restrict__ epsp,
    ushort16* __restrict__ uout, int n) {
  __shared__ uint32 ABs[65 * 64];  // packed bf16 A|B<<16: 16.6 KB
  {
    const uint4* g4 = (const uint4*)ABp;
    uint4* s4 = (uint4*)ABs;
    for (int i = threadIdx.x; i < 65 * 16; i += 256) s4[i] = g4[i];
  }
  __syncthreads();
  const uint32 lane = threadIdx.x & 63;
  const int wid = threadIdx.x >> 6;
  const float scale = 1.0f + epsp[0];
  for (int node = blockIdx.x * 4 + wid; node < n; node += gridDim.x * 4) {
    int s = offs[node], e = offs[node + 1];
    float acc = 0.0f;
    int i = s;
    for (; i + 7 < e; i += 8) {  // 8 gathers in flight
      int2 q[8]; float xv[8]; uint32 ab[8];
#pragma unroll
      for (int t = 0; t < 8; ++t) q[t] = pay[i + t];
#pragma unroll
      for (int t = 0; t < 8; ++t) {
        uint32 so = ((uint32)q[t].x & 0xFFFFFu) * 64u + lane;  // uint32 -> saddr+voffset
        xv[t] = bf2f(xb[so]);
        ab[t] = ABs[((uint32)q[t].x >> 20) * 64 + lane];
      }
#pragma unroll
      for (int t = 0; t < 8; ++t)
        acc += fmaxf(fmaf(__int_as_float(q[t].y), __uint_as_float(ab[t] << 16),
                          __uint_as_float(ab[t] & 0xffff0000u)) + xv[t], 0.0f);
    }
    for (; i < e; ++i) {
      int2 q0 = pay[i];
      uint32 so = ((uint32)q0.x & 0xFFFFFu) * 64u + lane;
      float x0 = bf2f(xb[so]);
      uint32 u0 = ABs[((uint32)q0.x >> 20) * 64 + lane];
      acc += fmaxf(fmaf(__int_as_float(q0.y), __uint_as_float(u0 << 16),
                        __uint_as_float(u0 & 0xffff0000u)) + x0, 0.0f);
    }
    float uval = fmaf(scale, xin[(size_t)node * 64 + lane], acc);
    uout[(size_t)node * 64 + lane] = f2bf(uval);  // u consumed only by k_mlp -> bf16 only
  }
}

// thread-per-node MLP; bf16 u rows in LDS (stride 66 ushorts: dword-aligned pair
// writes, <=2-way bank aliasing = free). 64 f32 reg accumulators per layer.
// Writes h as f32 (conv2 self-term + classify) AND bf16 (conv2 gather table).
__global__ __launch_bounds__(128) void k_mlp(
    const ushort16* __restrict__ uin, float* __restrict__ hout, ushort16* __restrict__ houtb,
    const float* __restrict__ W1, const float* __restrict__ B1,
    const float* __restrict__ W2, const float* __restrict__ B2, int n) {
  __shared__ unsigned short row[128 * 66];  // 16.9 KB
  const int tid = threadIdx.x;
  const size_t base = (size_t)blockIdx.x * 128 * 64;
  {
    const uint32* gu = (const uint32*)(uin + base);  // 4096 uints, node-major pairs
    uint32* rw = (uint32*)row;
    for (int k = 0; k < 32; ++k) {
      int g = k * 128 + tid;                 // node = g>>5, pair = g&31
      rw[(g >> 5) * 33 + (g & 31)] = gu[g];
    }
  }
  __syncthreads();
  const unsigned short* r16 = &row[tid * 66];
  uint32* rw32 = (uint32*)&row[tid * 66];    // tid*66*2 = 4*(33*tid): dword-aligned
  float h1[64];
#pragma unroll
  for (int i = 0; i < 64; ++i) h1[i] = B1[i];
  for (int j = 0; j < 64; ++j) {
    float uj = bf2f(r16[j]);
    const float* wr = &W1[j * 64];
#pragma unroll
    for (int i = 0; i < 64; ++i) h1[i] = fmaf(uj, wr[i], h1[i]);
  }
#pragma unroll
  for (int q = 0; q < 32; ++q) {             // relu -> own row, no sync needed
    uint32 lo = f2bf(fmaxf(h1[2 * q], 0.0f));
    uint32 hi = f2bf(fmaxf(h1[2 * q + 1], 0.0f));
    rw32[q] = lo | (hi << 16);
  }
  float h2[64];
#pragma unroll
  for (int i = 0; i < 64; ++i) h2[i] = B2[i];
  for (int j = 0; j < 64; ++j) {
    float uj = bf2f(r16[j]);
    const float* wr = &W2[j * 64];
#pragma unroll
    for (int i = 0; i < 64; ++i) h2[i] = fmaf(uj, wr[i], h2[i]);
  }
#pragma unroll
  for (int q = 0; q < 32; ++q) {
    uint32 lo = f2bf(fmaxf(h2[2 * q], 0.0f));
    uint32 hi = f2bf(fmaxf(h2[2 * q + 1], 0.0f));
    rw32[q] = lo | (hi << 16);
  }
  __syncthreads();
  for (int k = 0; k < 64; ++k) {             // coalesced f32 h
    int f = k * 128 + tid;                   // node = f>>6, feat = f&63
    hout[base + f] = bf2f(row[(f >> 6) * 66 + (f & 63)]);
  }
  {
    const uint32* rw = (const uint32*)row;
    uint32* ob = (uint32*)houtb;
    for (int k = 0; k < 32; ++k) {           // coalesced bf16 h (uint copy)
      int g = k * 128 + tid;
      ob[(base >> 1) + g] = rw[(g >> 5) * 33 + (g & 31)];
    }
  }
}

__global__ __launch_bounds__(128) void k_classify(
    const float* __restrict__ hin, const float* __restrict__ LW,
    const float* __restrict__ LB, float* __restrict__ out, int n) {
  __shared__ float row[128 * 65];
  const int tid = threadIdx.x;
  const size_t base = (size_t)blockIdx.x * 128 * 64;
  for (int k = 0; k < 64; ++k) {
    int f = k * 128 + tid;
    row[(f >> 6) * 65 + (f & 63)] = hin[base + f];
  }
  __syncthreads();
  int node = blockIdx.x * 128 + tid;
  float lg[40];
#pragma unroll
  for (int c = 0; c < 40; ++c) lg[c] = LB[c];
  const float* r = &row[tid * 65];
  for (int j = 0; j < 64; ++j) {
    float hj = r[j];
    const float* w = &LW[j * 40];
#pragma unroll
    for (int c = 0; c < 40; ++c) lg[c] = fmaf(hj, w[c], lg[c]);
  }
  if (node < n) {
    float mx = lg[0];
#pragma unroll
    for (int c = 1; c < 40; ++c) mx = fmaxf(mx, lg[c]);
    float se = 0.0f;
#pragma unroll
    for (int c = 0; c < 40; ++c) se += __expf(lg[c] - mx);
    float lse = mx + __logf(se);
    float* o = out + (size_t)node * 40;
#pragma unroll
    for (int q = 0; q < 10; ++q) {
      float4 v = make_float4(lg[q * 4] - lse, lg[q * 4 + 1] - lse,
                             lg[q * 4 + 2] - lse, lg[q * 4 + 3] - lse);
      *(float4*)(o + q * 4) = v;
    }
  }
}

extern "C" void kernel_launch(void* const* d_in, const int* in_sizes, int n_in,
                              void* d_out, int out_size, void* d_ws, size_t ws_size,
                              hipStream_t stream) {
  (void)n_in; (void)out_size; (void)ws_size;
  const float* x     = (const float*)d_in[0];
  const uint32* ei   = (const uint32*)d_in[1];
  const float* eattr = (const float*)d_in[2];
  const float* e_w1 = (const float*)d_in[3];
  const float* e_b1 = (const float*)d_in[4];
  const float* e_w2 = (const float*)d_in[5];
  const float* e_b2 = (const float*)d_in[6];
  const float* eps1 = (const float*)d_in[7];
  const float* m1w1 = (const float*)d_in[8];
  const float* m1b1 = (const float*)d_in[9];
  const float* m1w2 = (const float*)d_in[10];
  const float* m1b2 = (const float*)d_in[11];
  const float* eps2 = (const float*)d_in[12];
  const float* m2w1 = (const float*)d_in[13];
  const float* m2b1 = (const float*)d_in[14];
  const float* m2w2 = (const float*)d_in[15];
  const float* m2b2 = (const float*)d_in[16];
  const float* linw = (const float*)d_in[17];
  const float* linb = (const float*)d_in[18];

  const int N = in_sizes[0] / 64;
  const int E = in_sizes[1] / 2;
  const int NB128 = (N + 127) / 128;

  char* ws = (char*)d_ws;
  size_t off = 0;
  auto alloc = [&](size_t bytes, size_t align) {
    off = (off + align - 1) & ~(align - 1);
    size_t r = off; off += bytes; return r;
  };
  size_t oT    = alloc(64 * 4, 64);
  size_t oAB   = alloc(65 * 64 * 4, 64);
  size_t oH1   = alloc(1024 * 4, 128);
  size_t oBO   = alloc(1025 * 4, 128);
  size_t oBC   = alloc(1024 * 4, 128);
  size_t oOffs = alloc(((size_t)N + 1) * 4, 128);
  size_t oPay  = alloc((size_t)E * 8, 256);
  size_t oXb   = alloc((size_t)N * 64 * 2 + 32768, 256);   // bf16 gather table (+tail pad)
  size_t oU    = alloc((size_t)N * 64 * 2 + 32768, 1024);  // bf16 u (+tail pad)
  size_t oH    = alloc((size_t)N * 64 * 4 + 65536, 1024);  // f32 h (+tail pad)

  float*  tsS  = (float*)(ws + oT);
  uint32* ABp  = (uint32*)(ws + oAB);
  int*    h1   = (int*)(ws + oH1);
  int*    bOffs= (int*)(ws + oBO);
  int*    bCur = (int*)(ws + oBC);
  int*    offs = (int*)(ws + oOffs);
  int2*   pay  = (int2*)(ws + oPay);
  ushort16* xb = (ushort16*)(ws + oXb);
  ushort16* ubuf = (ushort16*)(ws + oU);
  float*  hbuf = (float*)(ws + oH);
  // partition scratch aliases hbuf (14.4 MB <= 25.7 MB); dead before k_mlp1 writes hbuf
  int*   srcp_arr = (int*)(ws + oH);
  float* a_arr    = (float*)(ws + oH + (size_t)E * 4);
  u8*    dstl_arr = (u8*)(ws + oH + (size_t)E * 8);

  hipMemsetAsync(ws + oH1, 0, 1024 * 4, stream);

  const int MB = (N + 127) / 128;
  const int CB = (N * 64 / 4 + 255) / 256;
  const int PB = (E + 2047) / 2048;

  k_setup<<<65, 256, 0, stream>>>(e_w1, e_b1, e_w2, e_b2, tsS, ABp);
  k_cast<<<CB, 256, 0, stream>>>(x, xb, N * 64 / 4);
  k_bcount<<<1024, 256, 0, stream>>>(ei, h1, E);
  k_bscan<<<1, 256, 0, stream>>>(h1, bOffs, bCur, offs, N, E);
  k_bpart<<<PB, 256, 0, stream>>>(ei, eattr, tsS, bCur, srcp_arr, a_arr, dstl_arr, E);
  k_blocal<<<NB128, 256, 0, stream>>>(bOffs, srcp_arr, a_arr, dstl_arr, offs, pay, N);
  k_conv<<<2048, 256, 0, stream>>>(x, xb, offs, pay, ABp, eps1, ubuf, N);
  k_mlp<<<MB, 128, 0, stream>>>(ubuf, hbuf, xb, m1w1, m1b1, m1w2, m1b2, N);
  k_conv<<<2048, 256, 0, stream>>>(hbuf, xb, offs, pay, ABp, eps2, ubuf, N);
  k_mlp<<<MB, 128, 0, stream>>>(ubuf, hbuf, xb, m2w1, m2b1, m2w2, m2b2, N);
  k_classify<<<MB, 128, 0, stream>>>(hbuf, linw, linb, (float*)d_out, N);
}